// Round 1
// baseline (722.093 us; speedup 1.0000x reference)
//
#include <hip/hip_runtime.h>
#include <math.h>

#define NODES 8192
#define NEDGE 262144
#define DIM 256

// ---------------- CSR build (dst-indexed) ----------------
__global__ void k_zero(int* __restrict__ deg) {
    int i = blockIdx.x * blockDim.x + threadIdx.x;
    if (i < NODES) deg[i] = 0;
}

__global__ void k_deg(const int* __restrict__ dst, int* __restrict__ deg) {
    int e = blockIdx.x * blockDim.x + threadIdx.x;
    if (e < NEDGE) atomicAdd(&deg[dst[e]], 1);
}

__global__ void k_scan(const int* __restrict__ deg, int* __restrict__ rowptr,
                       int* __restrict__ cursor) {
    __shared__ int part[256];
    int t = threadIdx.x;
    int base = t * 32;
    int local[32];
    int s = 0;
    for (int i = 0; i < 32; ++i) { local[i] = s; s += deg[base + i]; }
    part[t] = s;
    __syncthreads();
    for (int off = 1; off < 256; off <<= 1) {
        int v = (t >= off) ? part[t - off] : 0;
        __syncthreads();
        part[t] += v;
        __syncthreads();
    }
    int excl = (t == 0) ? 0 : part[t - 1];
    for (int i = 0; i < 32; ++i) {
        int v = excl + local[i];
        rowptr[base + i] = v;
        cursor[base + i] = v;
    }
    if (t == 255) rowptr[NODES] = part[255];
}

__global__ void k_fill(const int* __restrict__ dst, int* __restrict__ cursor,
                       int* __restrict__ elist) {
    int e = blockIdx.x * blockDim.x + threadIdx.x;
    if (e < NEDGE) {
        int pos = atomicAdd(&cursor[dst[e]], 1);
        elist[pos] = e;
    }
}

// ---------------- alpha = att_map . tanh(W (x_i*x_j) + b) ----------------
// 256 outputs x 64 edges per 256-thread block; 8x8 register tile per thread.
__global__ __launch_bounds__(256, 2) void k_alpha(
    const float* __restrict__ x, const int* __restrict__ src, const int* __restrict__ dst,
    const float* __restrict__ W, const float* __restrict__ bias, const float* __restrict__ amap,
    float* __restrict__ alpha)
{
    __shared__ float As[256][36];   // W rows, k-chunk of 32 (stride 36 -> conflict-free)
    __shared__ float Bs[64][36];    // p = x_i*x_j rows per edge
    __shared__ float red[32][64];
    const int tid = threadIdx.x;
    const int oo = tid >> 3;        // 0..31  (o = oo + 32*j)
    const int ee = tid & 7;         // 0..7   (e = ee + 8*je)
    const int e0 = blockIdx.x * 64;
    const int be  = tid >> 2;       // staging: edge 0..63
    const int bks = tid & 3;        // staging: k-subchunk (8 floats)
    const int es = src[e0 + be];
    const int ed = dst[e0 + be];
    const float* xs = x + (size_t)es * DIM + bks * 8;
    const float* xd = x + (size_t)ed * DIM + bks * 8;

    float acc[8][8];
#pragma unroll
    for (int j = 0; j < 8; ++j)
#pragma unroll
        for (int je = 0; je < 8; ++je) acc[j][je] = 0.f;

    for (int kc = 0; kc < DIM; kc += 32) {
        // stage A: thread stages W[tid][kc..kc+32)
        {
            const float4* g = (const float4*)(W + (size_t)tid * DIM + kc);
            float4* l = (float4*)(&As[tid][0]);
#pragma unroll
            for (int i = 0; i < 8; ++i) l[i] = g[i];
        }
        // stage B: p[k][e] for this chunk
        {
            float4 s0 = *(const float4*)(xs + kc);
            float4 s1 = *(const float4*)(xs + kc + 4);
            float4 d0 = *(const float4*)(xd + kc);
            float4 d1 = *(const float4*)(xd + kc + 4);
            float4 p0, p1;
            p0.x = s0.x * d0.x; p0.y = s0.y * d0.y; p0.z = s0.z * d0.z; p0.w = s0.w * d0.w;
            p1.x = s1.x * d1.x; p1.y = s1.y * d1.y; p1.z = s1.z * d1.z; p1.w = s1.w * d1.w;
            *(float4*)(&Bs[be][bks * 8])     = p0;
            *(float4*)(&Bs[be][bks * 8 + 4]) = p1;
        }
        __syncthreads();
#pragma unroll
        for (int kq = 0; kq < 8; ++kq) {
            float4 av[8], bv[8];
#pragma unroll
            for (int j = 0; j < 8; ++j)  av[j] = *(const float4*)(&As[oo + 32 * j][kq * 4]);
#pragma unroll
            for (int je = 0; je < 8; ++je) bv[je] = *(const float4*)(&Bs[ee + 8 * je][kq * 4]);
#pragma unroll
            for (int j = 0; j < 8; ++j)
#pragma unroll
                for (int je = 0; je < 8; ++je) {
                    acc[j][je] += av[j].x * bv[je].x;
                    acc[j][je] += av[j].y * bv[je].y;
                    acc[j][je] += av[j].z * bv[je].z;
                    acc[j][je] += av[j].w * bv[je].w;
                }
        }
        __syncthreads();
    }

    // epilogue: sum_o amap[o] * tanh(acc + bias[o]) per edge
    float part[8];
#pragma unroll
    for (int je = 0; je < 8; ++je) part[je] = 0.f;
#pragma unroll
    for (int j = 0; j < 8; ++j) {
        int o = oo + 32 * j;
        float bo = bias[o], ao = amap[o];
#pragma unroll
        for (int je = 0; je < 8; ++je)
            part[je] += ao * tanhf(acc[j][je] + bo);
    }
#pragma unroll
    for (int je = 0; je < 8; ++je) red[oo][ee + 8 * je] = part[je];
    __syncthreads();
    if (tid < 64) {
        float s = 0.f;
#pragma unroll 8
        for (int g = 0; g < 32; ++g) s += red[g][tid];
        alpha[e0 + tid] = s;
    }
}

// ---------------- per-node segment softmax + weighted aggregate ----------------
__global__ void k_aggregate(
    const float* __restrict__ x, const int* __restrict__ src,
    const float* __restrict__ alpha, const int* __restrict__ rowptr,
    const int* __restrict__ elist, float* __restrict__ agg)
{
    int gw = (blockIdx.x * blockDim.x + threadIdx.x) >> 6;
    int lane = threadIdx.x & 63;
    if (gw >= NODES) return;
    int start = rowptr[gw], end = rowptr[gw + 1];
    int deg = end - start;
    float m = -INFINITY;
    for (int i = lane; i < deg; i += 64) m = fmaxf(m, alpha[elist[start + i]]);
#pragma unroll
    for (int off = 32; off > 0; off >>= 1) m = fmaxf(m, __shfl_xor(m, off));
    float ssum = 0.f;
    for (int i = lane; i < deg; i += 64) ssum += expf(alpha[elist[start + i]] - m);
#pragma unroll
    for (int off = 32; off > 0; off >>= 1) ssum += __shfl_xor(ssum, off);
    float a0 = 0.f, a1 = 0.f, a2 = 0.f, a3 = 0.f;
    for (int i = 0; i < deg; ++i) {
        int e = elist[start + i];
        float w = expf(alpha[e] - m);
        const float4 v = *(const float4*)(x + (size_t)src[e] * DIM + lane * 4);
        a0 += w * v.x; a1 += w * v.y; a2 += w * v.z; a3 += w * v.w;
    }
    float inv = 1.f / (ssum + 1e-16f);
    float4 r; r.x = a0 * inv; r.y = a1 * inv; r.z = a2 * inv; r.w = a3 * inv;
    *(float4*)(agg + (size_t)gw * DIM + lane * 4) = r;
}

// ---------------- out = agg@pwa^T + x@pwo^T + biases ----------------
__global__ __launch_bounds__(256, 2) void k_out(
    const float* __restrict__ agg, const float* __restrict__ x,
    const float* __restrict__ Wa, const float* __restrict__ Wo,
    const float* __restrict__ ba, const float* __restrict__ bo,
    float* __restrict__ outb)
{
    __shared__ float As[256][36];
    __shared__ float Bs[64][36];
    __shared__ float Cs[64][68];
    const int tid = threadIdx.x;
    const int oo = tid >> 3, ee = tid & 7;
    const int n0 = blockIdx.x * 64;
    const int bn = tid >> 2, bks = tid & 3;

    float acc[8][8];
#pragma unroll
    for (int j = 0; j < 8; ++j)
#pragma unroll
        for (int je = 0; je < 8; ++je) acc[j][je] = 0.f;

    for (int cc = 0; cc < 16; ++cc) {
        const float* Wsrc = (cc < 8) ? Wa : Wo;
        const float* Bsrc = (cc < 8) ? agg : x;
        const int kc = (cc & 7) * 32;
        {
            const float4* g = (const float4*)(Wsrc + (size_t)tid * DIM + kc);
            float4* l = (float4*)(&As[tid][0]);
#pragma unroll
            for (int i = 0; i < 8; ++i) l[i] = g[i];
        }
        {
            const float4* g = (const float4*)(Bsrc + (size_t)(n0 + bn) * DIM + kc + bks * 8);
            *(float4*)(&Bs[bn][bks * 8])     = g[0];
            *(float4*)(&Bs[bn][bks * 8 + 4]) = g[1];
        }
        __syncthreads();
#pragma unroll
        for (int kq = 0; kq < 8; ++kq) {
            float4 av[8], bv[8];
#pragma unroll
            for (int j = 0; j < 8; ++j)  av[j] = *(const float4*)(&As[oo + 32 * j][kq * 4]);
#pragma unroll
            for (int je = 0; je < 8; ++je) bv[je] = *(const float4*)(&Bs[ee + 8 * je][kq * 4]);
#pragma unroll
            for (int j = 0; j < 8; ++j)
#pragma unroll
                for (int je = 0; je < 8; ++je) {
                    acc[j][je] += av[j].x * bv[je].x;
                    acc[j][je] += av[j].y * bv[je].y;
                    acc[j][je] += av[j].z * bv[je].z;
                    acc[j][je] += av[j].w * bv[je].w;
                }
        }
        __syncthreads();
    }

    float bsum[8];
#pragma unroll
    for (int j = 0; j < 8; ++j) bsum[j] = ba[oo + 32 * j] + bo[oo + 32 * j];

    // transpose through LDS in 4 chunks of 64 output-cols for coalesced stores
    for (int c = 0; c < 4; ++c) {
#pragma unroll
        for (int jh = 0; jh < 2; ++jh) {
            int j = 2 * c + jh;
#pragma unroll
            for (int je = 0; je < 8; ++je)
                Cs[ee + 8 * je][oo + 32 * jh] = acc[j][je] + bsum[j];
        }
        __syncthreads();
        int ol = tid & 63, wv = tid >> 6;
        for (int r = wv; r < 64; r += 4)
            outb[(size_t)(n0 + r) * DIM + c * 64 + ol] = Cs[r][ol];
        __syncthreads();
    }
}

// ---------------- BN column stats (fp64 partials) ----------------
__global__ void k_colstat(const float* __restrict__ outb, double* __restrict__ psum,
                          double* __restrict__ psq) {
    int g = blockIdx.x, t = threadIdx.x;
    double s = 0.0, q = 0.0;
    const float* p = outb + (size_t)g * 256 * DIM + t;
    for (int r = 0; r < 256; ++r) { double v = (double)p[(size_t)r * DIM]; s += v; q += v * v; }
    psum[g * DIM + t] = s;
    psq[g * DIM + t] = q;
}

__global__ void k_bnparam(const double* __restrict__ psum, const double* __restrict__ psq,
                          const float* __restrict__ gamma, const float* __restrict__ beta,
                          float* __restrict__ scale, float* __restrict__ shift) {
    int t = threadIdx.x;
    double s = 0.0, q = 0.0;
    for (int g = 0; g < 32; ++g) { s += psum[g * DIM + t]; q += psq[g * DIM + t]; }
    double mean = s / (double)NODES;
    double var = q / (double)NODES - mean * mean;
    float sc = (float)((double)gamma[t] / sqrt(var + 1e-5));
    scale[t] = sc;
    shift[t] = (float)((double)beta[t] - mean * (double)sc);
}

// ---------------- affine + SELU + pooling score ----------------
__global__ void k_bnselu(float* __restrict__ outb, const float* __restrict__ scale,
                         const float* __restrict__ shift, const float* __restrict__ yw,
                         const float* __restrict__ yb, float* __restrict__ y) {
    int gw = (blockIdx.x * blockDim.x + threadIdx.x) >> 6;
    int lane = threadIdx.x & 63;
    if (gw >= NODES) return;
    float4 v  = *(const float4*)(outb + (size_t)gw * DIM + lane * 4);
    float4 sc = *(const float4*)(scale + lane * 4);
    float4 sh = *(const float4*)(shift + lane * 4);
    const float SL = 1.0507009873554805f, SA = 1.6732632423543772f;
    float4 o;
    o.x = v.x * sc.x + sh.x;
    o.y = v.y * sc.y + sh.y;
    o.z = v.z * sc.z + sh.z;
    o.w = v.w * sc.w + sh.w;
    o.x = (o.x > 0.f) ? SL * o.x : SL * SA * expm1f(o.x);
    o.y = (o.y > 0.f) ? SL * o.y : SL * SA * expm1f(o.y);
    o.z = (o.z > 0.f) ? SL * o.z : SL * SA * expm1f(o.z);
    o.w = (o.w > 0.f) ? SL * o.w : SL * SA * expm1f(o.w);
    *(float4*)(outb + (size_t)gw * DIM + lane * 4) = o;
    float4 w = *(const float4*)(yw + lane * 4);
    float z = o.x * w.x + o.y * w.y + o.z * w.z + o.w * w.w;
#pragma unroll
    for (int off = 32; off > 0; off >>= 1) z += __shfl_xor(z, off);
    if (lane == 0) y[gw] = 1.f / (1.f + expf(-(z + yb[0])));
}

// ---------------- per-batch bitonic top-k (val desc, idx asc — jax semantics) ----------------
__global__ void k_topk(const float* __restrict__ y, float* __restrict__ svals,
                       int* __restrict__ sidx) {
    __shared__ float v[1024];
    __shared__ int  id[1024];
    int b = blockIdx.x, t = threadIdx.x;   // 512 threads
    v[t] = y[b * 1024 + t];           id[t] = t;
    v[t + 512] = y[b * 1024 + t + 512]; id[t + 512] = t + 512;
    __syncthreads();
    for (int k = 2; k <= 1024; k <<= 1) {
        for (int j = k >> 1; j > 0; j >>= 1) {
            for (int i = t; i < 1024; i += 512) {
                int l = i ^ j;
                if (l > i) {
                    float vi = v[i], vl = v[l];
                    int ii = id[i], il = id[l];
                    bool precede = (vi > vl) || (vi == vl && ii < il);
                    bool dirDesc = ((i & k) == 0);
                    bool sw = dirDesc ? !precede : precede;
                    if (sw) { v[i] = vl; v[l] = vi; id[i] = il; id[l] = ii; }
                }
            }
            __syncthreads();
        }
    }
    if (t < 512) { svals[b * 512 + t] = v[t]; sidx[b * 512 + t] = id[t]; }
}

// ---------------- gather + gate ----------------
__global__ void k_gather(const float* __restrict__ outb, const float* __restrict__ svals,
                         const int* __restrict__ sidx, float* __restrict__ dout) {
    int gw = (blockIdx.x * blockDim.x + threadIdx.x) >> 6;
    int lane = threadIdx.x & 63;
    int b = gw >> 9, r = gw & 511;
    float val = svals[b * 512 + r];
    int idn = sidx[b * 512 + r];
    float4 vv = *(const float4*)(outb + (size_t)(b * 1024 + idn) * DIM + lane * 4);
    vv.x *= val; vv.y *= val; vv.z *= val; vv.w *= val;
    *(float4*)(dout + (size_t)(b * 512 + r) * DIM + lane * 4) = vv;
}

extern "C" void kernel_launch(void* const* d_in, const int* in_sizes, int n_in,
                              void* d_out, int out_size, void* d_ws, size_t ws_size,
                              hipStream_t stream) {
    const float* x     = (const float*)d_in[0];
    const int* edges   = (const int*)d_in[1];
    const float* att_w = (const float*)d_in[2];
    const float* att_b = (const float*)d_in[3];
    const float* amap  = (const float*)d_in[4];
    const float* pwa_w = (const float*)d_in[5];
    const float* pwa_b = (const float*)d_in[6];
    const float* pwo_w = (const float*)d_in[7];
    const float* pwo_b = (const float*)d_in[8];
    const float* gamma = (const float*)d_in[9];
    const float* beta  = (const float*)d_in[10];
    const float* yw    = (const float*)d_in[11];
    const float* yb    = (const float*)d_in[12];
    float* out = (float*)d_out;
    const int* src = edges;
    const int* dst = edges + NEDGE;

    char* ws = (char*)d_ws;
    size_t off = 0;
    auto alloc = [&](size_t b) { void* p = ws + off; off = (off + b + 255) & ~(size_t)255; return p; };
    float* alpha  = (float*)alloc((size_t)NEDGE * 4);
    int*   elist  = (int*)alloc((size_t)NEDGE * 4);
    float* agg    = (float*)alloc((size_t)NODES * DIM * 4);
    float* outb   = (float*)alloc((size_t)NODES * DIM * 4);
    int*   deg    = (int*)alloc(NODES * 4);
    int*   rowptr = (int*)alloc((NODES + 1) * 4);
    int*   cursor = (int*)alloc(NODES * 4);
    double* psum  = (double*)alloc(32 * DIM * 8);
    double* psq   = (double*)alloc(32 * DIM * 8);
    float* scale  = (float*)alloc(DIM * 4);
    float* shift  = (float*)alloc(DIM * 4);
    float* yv     = (float*)alloc(NODES * 4);
    float* svals  = (float*)alloc(8 * 512 * 4);
    int*   sidx   = (int*)alloc(8 * 512 * 4);

    k_zero<<<NODES / 256, 256, 0, stream>>>(deg);
    k_deg<<<NEDGE / 256, 256, 0, stream>>>(dst, deg);
    k_scan<<<1, 256, 0, stream>>>(deg, rowptr, cursor);
    k_fill<<<NEDGE / 256, 256, 0, stream>>>(dst, cursor, elist);
    k_alpha<<<NEDGE / 64, 256, 0, stream>>>(x, src, dst, att_w, att_b, amap, alpha);
    k_aggregate<<<NODES / 4, 256, 0, stream>>>(x, src, alpha, rowptr, elist, agg);
    k_out<<<NODES / 64, 256, 0, stream>>>(agg, x, pwa_w, pwo_w, pwa_b, pwo_b, outb);
    k_colstat<<<32, 256, 0, stream>>>(outb, psum, psq);
    k_bnparam<<<1, 256, 0, stream>>>(psum, psq, gamma, beta, scale, shift);
    k_bnselu<<<NODES / 4, 256, 0, stream>>>(outb, scale, shift, yw, yb, yv);
    k_topk<<<8, 512, 0, stream>>>(yv, svals, sidx);
    k_gather<<<(8 * 512) / 4, 256, 0, stream>>>(outb, svals, sidx, out);
}

// Round 2
// 527.254 us; speedup vs baseline: 1.3695x; 1.3695x over previous
//
#include <hip/hip_runtime.h>
#include <math.h>

#define NODES 8192
#define NEDGE 262144
#define DIM 256

typedef float f32x4 __attribute__((ext_vector_type(4)));
typedef __bf16 bf16x8 __attribute__((ext_vector_type(8)));
typedef unsigned short u16;
typedef u16 u16x8 __attribute__((ext_vector_type(8)));

__device__ __forceinline__ u16 bf16r(float f) {
    unsigned u = __float_as_uint(f);
    u += 0x7FFFu + ((u >> 16) & 1u);
    return (u16)(u >> 16);
}
__device__ __forceinline__ float bfl(u16 s) { return __uint_as_float(((unsigned)s) << 16); }

// ---------------- CSR build (dst-indexed) ----------------
__global__ void k_zero(int* __restrict__ deg) {
    int i = blockIdx.x * blockDim.x + threadIdx.x;
    if (i < NODES) deg[i] = 0;
}

__global__ void k_deg(const int* __restrict__ dst, int* __restrict__ deg) {
    int e = blockIdx.x * blockDim.x + threadIdx.x;
    if (e < NEDGE) atomicAdd(&deg[dst[e]], 1);
}

__global__ void k_scan(const int* __restrict__ deg, int* __restrict__ rowptr,
                       int* __restrict__ cursor) {
    __shared__ int part[256];
    int t = threadIdx.x;
    int base = t * 32;
    int local[32];
    int s = 0;
    for (int i = 0; i < 32; ++i) { local[i] = s; s += deg[base + i]; }
    part[t] = s;
    __syncthreads();
    for (int off = 1; off < 256; off <<= 1) {
        int v = (t >= off) ? part[t - off] : 0;
        __syncthreads();
        part[t] += v;
        __syncthreads();
    }
    int excl = (t == 0) ? 0 : part[t - 1];
    for (int i = 0; i < 32; ++i) {
        int v = excl + local[i];
        rowptr[base + i] = v;
        cursor[base + i] = v;
    }
    if (t == 255) rowptr[NODES] = part[255];
}

__global__ void k_fill(const int* __restrict__ dst, int* __restrict__ cursor,
                       int* __restrict__ elist) {
    int e = blockIdx.x * blockDim.x + threadIdx.x;
    if (e < NEDGE) {
        int pos = atomicAdd(&cursor[dst[e]], 1);
        elist[pos] = e;
    }
}

// ---------------- W split into 3 bf16 planes ----------------
__global__ void k_wsplit(const float* __restrict__ W, u16* __restrict__ w1,
                         u16* __restrict__ w2, u16* __restrict__ w3) {
    int i = blockIdx.x * blockDim.x + threadIdx.x;
    if (i >= DIM * DIM) return;
    float f = W[i];
    u16 s1 = bf16r(f);  float r  = f - bfl(s1);
    u16 s2 = bf16r(r);  float r2 = r - bfl(s2);
    u16 s3 = bf16r(r2);
    w1[i] = s1; w2[i] = s2; w3[i] = s3;
}

// ---------------- alpha via 3-split bf16 MFMA ----------------
// Block: 256 thr (4 waves), 64 edges, 256 outs, K=256 in 2 chunks of 128.
// Wave w: M-tiles 4w..4w+3 (outs 64w..64w+63) x 4 N-tiles (all 64 edges).
__global__ __launch_bounds__(256, 2) void k_alpha_mfma(
    const float* __restrict__ x, const int* __restrict__ src, const int* __restrict__ dst,
    const u16* __restrict__ w1, const u16* __restrict__ w2, const u16* __restrict__ w3,
    const float* __restrict__ bias, const float* __restrict__ amap,
    float* __restrict__ alpha)
{
    __shared__ u16 p_lds[3][64][136];
    __shared__ float red[4][64];
    const int tid = threadIdx.x;
    const int w = tid >> 6;
    const int lane = tid & 63;
    const int c16 = lane & 15;
    const int g = lane >> 4;
    const int g8 = g * 8;
    const int e0 = blockIdx.x * 64;
    const int mrow = 64 * w + c16;

    // staging roles: edge = tid>>2, k-block of 32 = (tid&3)
    const int se = tid >> 2;
    const int kb = tid & 3;
    const int es = src[e0 + se];
    const int ed = dst[e0 + se];
    const float* xs = x + (size_t)es * DIM + kb * 32;
    const float* xd = x + (size_t)ed * DIM + kb * 32;

    float bias_r[16], amap_r[16];
#pragma unroll
    for (int t = 0; t < 4; ++t)
#pragma unroll
        for (int r = 0; r < 4; ++r) {
            int m = 64 * w + 16 * t + 4 * g + r;
            bias_r[t * 4 + r] = bias[m];
            amap_r[t * 4 + r] = amap[m];
        }

    f32x4 acc[4][4];
#pragma unroll
    for (int t = 0; t < 4; ++t)
#pragma unroll
        for (int nt = 0; nt < 4; ++nt) acc[t][nt] = (f32x4)0.f;

    bf16x8 afA[4][3], afB[4][3];
    const int PA[6] = {0, 0, 1, 0, 1, 2};
    const int PB[6] = {0, 1, 0, 2, 1, 0};

#define LOADA(buf, kg) { \
    _Pragma("unroll") for (int t = 0; t < 4; ++t) { \
        size_t ro = (size_t)(mrow + 16 * t) * DIM + (kg) + g8; \
        buf[t][0] = *(const bf16x8*)(const void*)(w1 + ro); \
        buf[t][1] = *(const bf16x8*)(const void*)(w2 + ro); \
        buf[t][2] = *(const bf16x8*)(const void*)(w3 + ro); } }

#define KSTEP(buf, kl) { \
    _Pragma("unroll") for (int pr = 0; pr < 6; ++pr) { \
        bf16x8 bfr[4]; \
        _Pragma("unroll") for (int nt = 0; nt < 4; ++nt) \
            bfr[nt] = *(const bf16x8*)(const void*)&p_lds[PB[pr]][nt * 16 + c16][(kl) + g8]; \
        _Pragma("unroll") for (int t = 0; t < 4; ++t) \
        _Pragma("unroll") for (int nt = 0; nt < 4; ++nt) \
            acc[t][nt] = __builtin_amdgcn_mfma_f32_16x16x32_bf16(buf[t][PA[pr]], bfr[nt], acc[t][nt], 0, 0, 0); } }

    for (int c = 0; c < 2; ++c) {
        if (c) __syncthreads();
        // stage p = x_src * x_dst, split 3-way into bf16 planes
#pragma unroll
        for (int q = 0; q < 4; ++q) {
            float4 a0 = *(const float4*)(xs + c * 128 + q * 8);
            float4 a1 = *(const float4*)(xs + c * 128 + q * 8 + 4);
            float4 b0 = *(const float4*)(xd + c * 128 + q * 8);
            float4 b1 = *(const float4*)(xd + c * 128 + q * 8 + 4);
            float p[8] = {a0.x * b0.x, a0.y * b0.y, a0.z * b0.z, a0.w * b0.w,
                          a1.x * b1.x, a1.y * b1.y, a1.z * b1.z, a1.w * b1.w};
            u16x8 v1, v2, v3;
#pragma unroll
            for (int i = 0; i < 8; ++i) {
                u16 s1 = bf16r(p[i]); float r  = p[i] - bfl(s1);
                u16 s2 = bf16r(r);    float r2 = r - bfl(s2);
                u16 s3 = bf16r(r2);
                v1[i] = s1; v2[i] = s2; v3[i] = s3;
            }
            *(u16x8*)&p_lds[0][se][kb * 32 + q * 8] = v1;
            *(u16x8*)&p_lds[1][se][kb * 32 + q * 8] = v2;
            *(u16x8*)&p_lds[2][se][kb * 32 + q * 8] = v3;
        }
        __syncthreads();
        LOADA(afA, c * 128 + 0);
        LOADA(afB, c * 128 + 32);
        KSTEP(afA, 0);
        LOADA(afA, c * 128 + 64);
        KSTEP(afB, 32);
        LOADA(afB, c * 128 + 96);
        KSTEP(afA, 64);
        KSTEP(afB, 96);
    }

    // epilogue: per edge, sum over this wave's 64 outs of amap*tanh(h+bias)
    float part[4] = {0.f, 0.f, 0.f, 0.f};
#pragma unroll
    for (int t = 0; t < 4; ++t)
#pragma unroll
        for (int nt = 0; nt < 4; ++nt)
#pragma unroll
            for (int r = 0; r < 4; ++r)
                part[nt] += amap_r[t * 4 + r] * tanhf(acc[t][nt][r] + bias_r[t * 4 + r]);
#pragma unroll
    for (int nt = 0; nt < 4; ++nt) {
        float p = part[nt];
        p += __shfl_xor(p, 16);
        p += __shfl_xor(p, 32);
        if (lane < 16) red[w][nt * 16 + c16] = p;
    }
    __syncthreads();
    if (tid < 64) alpha[e0 + tid] = red[0][tid] + red[1][tid] + red[2][tid] + red[3][tid];
}

// ---------------- per-node segment softmax + weighted aggregate ----------------
__global__ void k_aggregate(
    const float* __restrict__ x, const int* __restrict__ src,
    const float* __restrict__ alpha, const int* __restrict__ rowptr,
    const int* __restrict__ elist, float* __restrict__ agg)
{
    int gw = (blockIdx.x * blockDim.x + threadIdx.x) >> 6;
    int lane = threadIdx.x & 63;
    if (gw >= NODES) return;
    int start = rowptr[gw], end = rowptr[gw + 1];
    int deg = end - start;
    float m = -INFINITY;
    for (int i = lane; i < deg; i += 64) m = fmaxf(m, alpha[elist[start + i]]);
#pragma unroll
    for (int off = 32; off > 0; off >>= 1) m = fmaxf(m, __shfl_xor(m, off));
    float ssum = 0.f;
    for (int i = lane; i < deg; i += 64) ssum += expf(alpha[elist[start + i]] - m);
#pragma unroll
    for (int off = 32; off > 0; off >>= 1) ssum += __shfl_xor(ssum, off);
    float a0 = 0.f, a1 = 0.f, a2 = 0.f, a3 = 0.f;
    for (int i = 0; i < deg; ++i) {
        int e = elist[start + i];
        float w = expf(alpha[e] - m);
        const float4 v = *(const float4*)(x + (size_t)src[e] * DIM + lane * 4);
        a0 += w * v.x; a1 += w * v.y; a2 += w * v.z; a3 += w * v.w;
    }
    float inv = 1.f / (ssum + 1e-16f);
    float4 r; r.x = a0 * inv; r.y = a1 * inv; r.z = a2 * inv; r.w = a3 * inv;
    *(float4*)(agg + (size_t)gw * DIM + lane * 4) = r;
}

// ---------------- out = agg@pwa^T + x@pwo^T + biases ----------------
__global__ __launch_bounds__(256, 2) void k_out(
    const float* __restrict__ agg, const float* __restrict__ x,
    const float* __restrict__ Wa, const float* __restrict__ Wo,
    const float* __restrict__ ba, const float* __restrict__ bo,
    float* __restrict__ outb)
{
    __shared__ float As[256][36];
    __shared__ float Bs[64][36];
    __shared__ float Cs[64][68];
    const int tid = threadIdx.x;
    const int oo = tid >> 3, ee = tid & 7;
    const int n0 = blockIdx.x * 64;
    const int bn = tid >> 2, bks = tid & 3;

    float acc[8][8];
#pragma unroll
    for (int j = 0; j < 8; ++j)
#pragma unroll
        for (int je = 0; je < 8; ++je) acc[j][je] = 0.f;

    for (int cc = 0; cc < 16; ++cc) {
        const float* Wsrc = (cc < 8) ? Wa : Wo;
        const float* Bsrc = (cc < 8) ? agg : x;
        const int kc = (cc & 7) * 32;
        {
            const float4* g = (const float4*)(Wsrc + (size_t)tid * DIM + kc);
            float4* l = (float4*)(&As[tid][0]);
#pragma unroll
            for (int i = 0; i < 8; ++i) l[i] = g[i];
        }
        {
            const float4* g = (const float4*)(Bsrc + (size_t)(n0 + bn) * DIM + kc + bks * 8);
            *(float4*)(&Bs[bn][bks * 8])     = g[0];
            *(float4*)(&Bs[bn][bks * 8 + 4]) = g[1];
        }
        __syncthreads();
#pragma unroll
        for (int kq = 0; kq < 8; ++kq) {
            float4 av[8], bv[8];
#pragma unroll
            for (int j = 0; j < 8; ++j)  av[j] = *(const float4*)(&As[oo + 32 * j][kq * 4]);
#pragma unroll
            for (int je = 0; je < 8; ++je) bv[je] = *(const float4*)(&Bs[ee + 8 * je][kq * 4]);
#pragma unroll
            for (int j = 0; j < 8; ++j)
#pragma unroll
                for (int je = 0; je < 8; ++je) {
                    acc[j][je] += av[j].x * bv[je].x;
                    acc[j][je] += av[j].y * bv[je].y;
                    acc[j][je] += av[j].z * bv[je].z;
                    acc[j][je] += av[j].w * bv[je].w;
                }
        }
        __syncthreads();
    }

    float bsum[8];
#pragma unroll
    for (int j = 0; j < 8; ++j) bsum[j] = ba[oo + 32 * j] + bo[oo + 32 * j];

    for (int c = 0; c < 4; ++c) {
#pragma unroll
        for (int jh = 0; jh < 2; ++jh) {
            int j = 2 * c + jh;
#pragma unroll
            for (int je = 0; je < 8; ++je)
                Cs[ee + 8 * je][oo + 32 * jh] = acc[j][je] + bsum[j];
        }
        __syncthreads();
        int ol = tid & 63, wv = tid >> 6;
        for (int r = wv; r < 64; r += 4)
            outb[(size_t)(n0 + r) * DIM + c * 64 + ol] = Cs[r][ol];
        __syncthreads();
    }
}

// ---------------- BN column stats (fp64 partials) ----------------
__global__ void k_colstat(const float* __restrict__ outb, double* __restrict__ psum,
                          double* __restrict__ psq) {
    int g = blockIdx.x, t = threadIdx.x;
    double s = 0.0, q = 0.0;
    const float* p = outb + (size_t)g * 256 * DIM + t;
    for (int r = 0; r < 256; ++r) { double v = (double)p[(size_t)r * DIM]; s += v; q += v * v; }
    psum[g * DIM + t] = s;
    psq[g * DIM + t] = q;
}

__global__ void k_bnparam(const double* __restrict__ psum, const double* __restrict__ psq,
                          const float* __restrict__ gamma, const float* __restrict__ beta,
                          float* __restrict__ scale, float* __restrict__ shift) {
    int t = threadIdx.x;
    double s = 0.0, q = 0.0;
    for (int g = 0; g < 32; ++g) { s += psum[g * DIM + t]; q += psq[g * DIM + t]; }
    double mean = s / (double)NODES;
    double var = q / (double)NODES - mean * mean;
    float sc = (float)((double)gamma[t] / sqrt(var + 1e-5));
    scale[t] = sc;
    shift[t] = (float)((double)beta[t] - mean * (double)sc);
}

// ---------------- affine + SELU + pooling score ----------------
__global__ void k_bnselu(float* __restrict__ outb, const float* __restrict__ scale,
                         const float* __restrict__ shift, const float* __restrict__ yw,
                         const float* __restrict__ yb, float* __restrict__ y) {
    int gw = (blockIdx.x * blockDim.x + threadIdx.x) >> 6;
    int lane = threadIdx.x & 63;
    if (gw >= NODES) return;
    float4 v  = *(const float4*)(outb + (size_t)gw * DIM + lane * 4);
    float4 sc = *(const float4*)(scale + lane * 4);
    float4 sh = *(const float4*)(shift + lane * 4);
    const float SL = 1.0507009873554805f, SA = 1.6732632423543772f;
    float4 o;
    o.x = v.x * sc.x + sh.x;
    o.y = v.y * sc.y + sh.y;
    o.z = v.z * sc.z + sh.z;
    o.w = v.w * sc.w + sh.w;
    o.x = (o.x > 0.f) ? SL * o.x : SL * SA * expm1f(o.x);
    o.y = (o.y > 0.f) ? SL * o.y : SL * SA * expm1f(o.y);
    o.z = (o.z > 0.f) ? SL * o.z : SL * SA * expm1f(o.z);
    o.w = (o.w > 0.f) ? SL * o.w : SL * SA * expm1f(o.w);
    *(float4*)(outb + (size_t)gw * DIM + lane * 4) = o;
    float4 w = *(const float4*)(yw + lane * 4);
    float z = o.x * w.x + o.y * w.y + o.z * w.z + o.w * w.w;
#pragma unroll
    for (int off = 32; off > 0; off >>= 1) z += __shfl_xor(z, off);
    if (lane == 0) y[gw] = 1.f / (1.f + expf(-(z + yb[0])));
}

// ---------------- per-batch bitonic top-k (val desc, idx asc — jax semantics) ----------------
__global__ void k_topk(const float* __restrict__ y, float* __restrict__ svals,
                       int* __restrict__ sidx) {
    __shared__ float v[1024];
    __shared__ int  id[1024];
    int b = blockIdx.x, t = threadIdx.x;   // 512 threads
    v[t] = y[b * 1024 + t];           id[t] = t;
    v[t + 512] = y[b * 1024 + t + 512]; id[t + 512] = t + 512;
    __syncthreads();
    for (int k = 2; k <= 1024; k <<= 1) {
        for (int j = k >> 1; j > 0; j >>= 1) {
            for (int i = t; i < 1024; i += 512) {
                int l = i ^ j;
                if (l > i) {
                    float vi = v[i], vl = v[l];
                    int ii = id[i], il = id[l];
                    bool precede = (vi > vl) || (vi == vl && ii < il);
                    bool dirDesc = ((i & k) == 0);
                    bool sw = dirDesc ? !precede : precede;
                    if (sw) { v[i] = vl; v[l] = vi; id[i] = il; id[l] = ii; }
                }
            }
            __syncthreads();
        }
    }
    if (t < 512) { svals[b * 512 + t] = v[t]; sidx[b * 512 + t] = id[t]; }
}

// ---------------- gather + gate ----------------
__global__ void k_gather(const float* __restrict__ outb, const float* __restrict__ svals,
                         const int* __restrict__ sidx, float* __restrict__ dout) {
    int gw = (blockIdx.x * blockDim.x + threadIdx.x) >> 6;
    int lane = threadIdx.x & 63;
    int b = gw >> 9, r = gw & 511;
    float val = svals[b * 512 + r];
    int idn = sidx[b * 512 + r];
    float4 vv = *(const float4*)(outb + (size_t)(b * 1024 + idn) * DIM + lane * 4);
    vv.x *= val; vv.y *= val; vv.z *= val; vv.w *= val;
    *(float4*)(dout + (size_t)(b * 512 + r) * DIM + lane * 4) = vv;
}

extern "C" void kernel_launch(void* const* d_in, const int* in_sizes, int n_in,
                              void* d_out, int out_size, void* d_ws, size_t ws_size,
                              hipStream_t stream) {
    const float* x     = (const float*)d_in[0];
    const int* edges   = (const int*)d_in[1];
    const float* att_w = (const float*)d_in[2];
    const float* att_b = (const float*)d_in[3];
    const float* amap  = (const float*)d_in[4];
    const float* pwa_w = (const float*)d_in[5];
    const float* pwa_b = (const float*)d_in[6];
    const float* pwo_w = (const float*)d_in[7];
    const float* pwo_b = (const float*)d_in[8];
    const float* gamma = (const float*)d_in[9];
    const float* beta  = (const float*)d_in[10];
    const float* yw    = (const float*)d_in[11];
    const float* yb    = (const float*)d_in[12];
    float* out = (float*)d_out;
    const int* src = edges;
    const int* dst = edges + NEDGE;

    char* ws = (char*)d_ws;
    size_t off = 0;
    auto alloc = [&](size_t b) { void* p = ws + off; off = (off + b + 255) & ~(size_t)255; return p; };
    float* alpha  = (float*)alloc((size_t)NEDGE * 4);
    int*   elist  = (int*)alloc((size_t)NEDGE * 4);
    float* agg    = (float*)alloc((size_t)NODES * DIM * 4);
    float* outb   = (float*)alloc((size_t)NODES * DIM * 4);
    int*   deg    = (int*)alloc(NODES * 4);
    int*   rowptr = (int*)alloc((NODES + 1) * 4);
    int*   cursor = (int*)alloc(NODES * 4);
    double* psum  = (double*)alloc(32 * DIM * 8);
    double* psq   = (double*)alloc(32 * DIM * 8);
    float* scale  = (float*)alloc(DIM * 4);
    float* shift  = (float*)alloc(DIM * 4);
    float* yv     = (float*)alloc(NODES * 4);
    float* svals  = (float*)alloc(8 * 512 * 4);
    int*   sidx   = (int*)alloc(8 * 512 * 4);
    u16*   w1     = (u16*)alloc((size_t)DIM * DIM * 2);
    u16*   w2     = (u16*)alloc((size_t)DIM * DIM * 2);
    u16*   w3     = (u16*)alloc((size_t)DIM * DIM * 2);

    k_wsplit<<<DIM * DIM / 256, 256, 0, stream>>>(att_w, w1, w2, w3);
    k_zero<<<NODES / 256, 256, 0, stream>>>(deg);
    k_deg<<<NEDGE / 256, 256, 0, stream>>>(dst, deg);
    k_scan<<<1, 256, 0, stream>>>(deg, rowptr, cursor);
    k_fill<<<NEDGE / 256, 256, 0, stream>>>(dst, cursor, elist);
    k_alpha_mfma<<<NEDGE / 64, 256, 0, stream>>>(x, src, dst, w1, w2, w3, att_b, amap, alpha);
    k_aggregate<<<NODES / 4, 256, 0, stream>>>(x, src, alpha, rowptr, elist, agg);
    k_out<<<NODES / 64, 256, 0, stream>>>(agg, x, pwa_w, pwo_w, pwa_b, pwo_b, outb);
    k_colstat<<<32, 256, 0, stream>>>(outb, psum, psq);
    k_bnparam<<<1, 256, 0, stream>>>(psum, psq, gamma, beta, scale, shift);
    k_bnselu<<<NODES / 4, 256, 0, stream>>>(outb, scale, shift, yw, yb, yv);
    k_topk<<<8, 512, 0, stream>>>(yv, svals, sidx);
    k_gather<<<(8 * 512) / 4, 256, 0, stream>>>(outb, svals, sidx, out);
}

// Round 3
// 523.951 us; speedup vs baseline: 1.3782x; 1.0063x over previous
//
#include <hip/hip_runtime.h>
#include <math.h>

#define NODES 8192
#define NEDGE 262144
#define DIM 256

typedef float f32x4 __attribute__((ext_vector_type(4)));
typedef __bf16 bf16x8 __attribute__((ext_vector_type(8)));
typedef unsigned short u16;
typedef u16 u16x8 __attribute__((ext_vector_type(8)));

__device__ __forceinline__ u16 bf16r(float f) {
    unsigned u = __float_as_uint(f);
    u += 0x7FFFu + ((u >> 16) & 1u);
    return (u16)(u >> 16);
}
__device__ __forceinline__ float bfl(u16 s) { return __uint_as_float(((unsigned)s) << 16); }

// ---------------- CSR build (dst-indexed) ----------------
__global__ void k_zero(int* __restrict__ deg) {
    int i = blockIdx.x * blockDim.x + threadIdx.x;
    if (i < NODES) deg[i] = 0;
}

__global__ void k_deg(const int* __restrict__ dst, int* __restrict__ deg) {
    int e = blockIdx.x * blockDim.x + threadIdx.x;
    if (e < NEDGE) atomicAdd(&deg[dst[e]], 1);
}

__global__ void k_scan(const int* __restrict__ deg, int* __restrict__ rowptr,
                       int* __restrict__ cursor) {
    __shared__ int part[256];
    int t = threadIdx.x;
    int base = t * 32;
    int local[32];
    int s = 0;
    for (int i = 0; i < 32; ++i) { local[i] = s; s += deg[base + i]; }
    part[t] = s;
    __syncthreads();
    for (int off = 1; off < 256; off <<= 1) {
        int v = (t >= off) ? part[t - off] : 0;
        __syncthreads();
        part[t] += v;
        __syncthreads();
    }
    int excl = (t == 0) ? 0 : part[t - 1];
    for (int i = 0; i < 32; ++i) {
        int v = excl + local[i];
        rowptr[base + i] = v;
        cursor[base + i] = v;
    }
    if (t == 255) rowptr[NODES] = part[255];
}

__global__ void k_fill(const int* __restrict__ dst, int* __restrict__ cursor,
                       int* __restrict__ elist) {
    int e = blockIdx.x * blockDim.x + threadIdx.x;
    if (e < NEDGE) {
        int pos = atomicAdd(&cursor[dst[e]], 1);
        elist[pos] = e;
    }
}

// ---------------- W split into 3 bf16 planes (RN, one-time) ----------------
__global__ void k_wsplit(const float* __restrict__ W, u16* __restrict__ w1,
                         u16* __restrict__ w2, u16* __restrict__ w3) {
    int i = blockIdx.x * blockDim.x + threadIdx.x;
    if (i >= DIM * DIM) return;
    float f = W[i];
    u16 s1 = bf16r(f);  float r  = f - bfl(s1);
    u16 s2 = bf16r(r);  float r2 = r - bfl(s2);
    u16 s3 = bf16r(r2);
    w1[i] = s1; w2[i] = s2; w3[i] = s3;
}

// ---------------- alpha via 3-split bf16 MFMA, v3 ----------------
// Block: 256 thr (4 waves), 64 edges, 256 outs. Wave w: outs [64w,64w+64),
// 4x4 tiles of 16x16x32 MFMA. K in 2 chunks of 128; p (=x_i*x_j) staged in
// LDS as [plane][kblock(8 u16)][edge][8] -> all LDS ops 256B-contiguous per
// 16-lane phase (conflict-free). A (W planes) streamed from global/L2.
// Per k-offset: 12 A-frag loads + 12 B-frag LDS reads feed a 96-MFMA burst.
__global__ __launch_bounds__(256, 2) void k_alpha_v3(
    const float* __restrict__ x, const int* __restrict__ src, const int* __restrict__ dst,
    const u16* __restrict__ w1, const u16* __restrict__ w2, const u16* __restrict__ w3,
    const float* __restrict__ bias, const float* __restrict__ amap,
    float* __restrict__ alpha)
{
    __shared__ u16 p_lds[3][16][64][8];
    __shared__ float red[4][64];
    const int tid = threadIdx.x;
    const int w = tid >> 6;
    const int lane = tid & 63;
    const int c16 = lane & 15;
    const int g = lane >> 4;
    const int e0 = blockIdx.x * 64;

    // staging role: edge = lane, k-quarter (32 floats) = wave id
    const int se = lane;
    const int kb = w;
    const int es = src[e0 + se];
    const int ed = dst[e0 + se];
    const float* xs = x + (size_t)es * DIM + kb * 32;
    const float* xd = x + (size_t)ed * DIM + kb * 32;

    const u16* wp0 = w1; const u16* wp1 = w2; const u16* wp2 = w3;

    float bias_r[16], amap_r[16];
#pragma unroll
    for (int t = 0; t < 4; ++t)
#pragma unroll
        for (int r = 0; r < 4; ++r) {
            int m = 64 * w + 16 * t + 4 * g + r;
            bias_r[t * 4 + r] = bias[m];
            amap_r[t * 4 + r] = amap[m];
        }

    f32x4 acc[4][4];
#pragma unroll
    for (int t = 0; t < 4; ++t)
#pragma unroll
        for (int nt = 0; nt < 4; ++nt) acc[t][nt] = (f32x4)0.f;

    for (int c = 0; c < 2; ++c) {
        if (c) __syncthreads();
        // ---- stage: thread computes p for (edge se, 32 k-values) ----
        {
            float4 sv[8], dv[8];
#pragma unroll
            for (int j = 0; j < 8; ++j) sv[j] = *(const float4*)(xs + c * 128 + j * 4);
#pragma unroll
            for (int j = 0; j < 8; ++j) dv[j] = *(const float4*)(xd + c * 128 + j * 4);
#pragma unroll
            for (int q = 0; q < 4; ++q) {
                u16x8 v1, v2, v3;
#pragma unroll
                for (int i = 0; i < 8; ++i) {
                    int idx = q * 8 + i;
                    float a = ((const float*)sv)[idx];
                    float b = ((const float*)dv)[idx];
                    float f = a * b;
                    unsigned uf = __float_as_uint(f);
                    float r = f - __uint_as_float(uf & 0xFFFF0000u);
                    unsigned ur = __float_as_uint(r);
                    float r2 = r - __uint_as_float(ur & 0xFFFF0000u);
                    unsigned ur2 = __float_as_uint(r2);
                    v1[i] = (u16)(uf >> 16);
                    v2[i] = (u16)(ur >> 16);
                    v3[i] = (u16)(ur2 >> 16);
                }
                *(u16x8*)&p_lds[0][kb * 4 + q][se][0] = v1;
                *(u16x8*)&p_lds[1][kb * 4 + q][se][0] = v2;
                *(u16x8*)&p_lds[2][kb * 4 + q][se][0] = v3;
            }
        }
        __syncthreads();

        // ---- 4 k-offsets of 32 ----
#pragma unroll
        for (int koi = 0; koi < 4; ++koi) {
            bf16x8 af[4][3], bf[4][3];
#pragma unroll
            for (int t = 0; t < 4; ++t) {
                size_t ro = (size_t)(64 * w + 16 * t + c16) * DIM + c * 128 + koi * 32 + g * 8;
                af[t][0] = *(const bf16x8*)(const void*)(wp0 + ro);
                af[t][1] = *(const bf16x8*)(const void*)(wp1 + ro);
                af[t][2] = *(const bf16x8*)(const void*)(wp2 + ro);
            }
#pragma unroll
            for (int nt = 0; nt < 4; ++nt) {
#pragma unroll
                for (int pl = 0; pl < 3; ++pl)
                    bf[nt][pl] = *(const bf16x8*)(const void*)&p_lds[pl][koi * 4 + g][nt * 16 + c16][0];
            }
            // 6 products: (1,1) (1,2) (2,1) (1,3) (2,2) (3,1) — 96 dependency-free MFMAs
#pragma unroll
            for (int pr = 0; pr < 6; ++pr) {
                const int PA[6] = {0, 0, 1, 0, 1, 2};
                const int PB[6] = {0, 1, 0, 2, 1, 0};
#pragma unroll
                for (int t = 0; t < 4; ++t)
#pragma unroll
                    for (int nt = 0; nt < 4; ++nt)
                        acc[t][nt] = __builtin_amdgcn_mfma_f32_16x16x32_bf16(
                            af[t][PA[pr]], bf[nt][PB[pr]], acc[t][nt], 0, 0, 0);
            }
        }
    }

    // ---- epilogue: alpha[e] = sum_out amap*tanh(h+bias) ----
    float part[4] = {0.f, 0.f, 0.f, 0.f};
#pragma unroll
    for (int t = 0; t < 4; ++t)
#pragma unroll
        for (int nt = 0; nt < 4; ++nt)
#pragma unroll
            for (int r = 0; r < 4; ++r)
                part[nt] += amap_r[t * 4 + r] * tanhf(acc[t][nt][r] + bias_r[t * 4 + r]);
#pragma unroll
    for (int nt = 0; nt < 4; ++nt) {
        float p = part[nt];
        p += __shfl_xor(p, 16);
        p += __shfl_xor(p, 32);
        if (lane < 16) red[w][nt * 16 + c16] = p;
    }
    __syncthreads();
    if (tid < 64) alpha[e0 + tid] = red[0][tid] + red[1][tid] + red[2][tid] + red[3][tid];
}

// ---------------- per-node segment softmax + weighted aggregate ----------------
__global__ void k_aggregate(
    const float* __restrict__ x, const int* __restrict__ src,
    const float* __restrict__ alpha, const int* __restrict__ rowptr,
    const int* __restrict__ elist, float* __restrict__ agg)
{
    int gw = (blockIdx.x * blockDim.x + threadIdx.x) >> 6;
    int lane = threadIdx.x & 63;
    if (gw >= NODES) return;
    int start = rowptr[gw], end = rowptr[gw + 1];
    int deg = end - start;
    float m = -INFINITY;
    for (int i = lane; i < deg; i += 64) m = fmaxf(m, alpha[elist[start + i]]);
#pragma unroll
    for (int off = 32; off > 0; off >>= 1) m = fmaxf(m, __shfl_xor(m, off));
    float ssum = 0.f;
    for (int i = lane; i < deg; i += 64) ssum += expf(alpha[elist[start + i]] - m);
#pragma unroll
    for (int off = 32; off > 0; off >>= 1) ssum += __shfl_xor(ssum, off);
    float a0 = 0.f, a1 = 0.f, a2 = 0.f, a3 = 0.f;
    for (int i = 0; i < deg; ++i) {
        int e = elist[start + i];
        float w = expf(alpha[e] - m);
        const float4 v = *(const float4*)(x + (size_t)src[e] * DIM + lane * 4);
        a0 += w * v.x; a1 += w * v.y; a2 += w * v.z; a3 += w * v.w;
    }
    float inv = 1.f / (ssum + 1e-16f);
    float4 r; r.x = a0 * inv; r.y = a1 * inv; r.z = a2 * inv; r.w = a3 * inv;
    *(float4*)(agg + (size_t)gw * DIM + lane * 4) = r;
}

// ---------------- out = agg@pwa^T + x@pwo^T + biases ----------------
__global__ __launch_bounds__(256, 2) void k_out(
    const float* __restrict__ agg, const float* __restrict__ x,
    const float* __restrict__ Wa, const float* __restrict__ Wo,
    const float* __restrict__ ba, const float* __restrict__ bo,
    float* __restrict__ outb)
{
    __shared__ float As[256][36];
    __shared__ float Bs[64][36];
    __shared__ float Cs[64][68];
    const int tid = threadIdx.x;
    const int oo = tid >> 3, ee = tid & 7;
    const int n0 = blockIdx.x * 64;
    const int bn = tid >> 2, bks = tid & 3;

    float acc[8][8];
#pragma unroll
    for (int j = 0; j < 8; ++j)
#pragma unroll
        for (int je = 0; je < 8; ++je) acc[j][je] = 0.f;

    for (int cc = 0; cc < 16; ++cc) {
        const float* Wsrc = (cc < 8) ? Wa : Wo;
        const float* Bsrc = (cc < 8) ? agg : x;
        const int kc = (cc & 7) * 32;
        {
            const float4* g = (const float4*)(Wsrc + (size_t)tid * DIM + kc);
            float4* l = (float4*)(&As[tid][0]);
#pragma unroll
            for (int i = 0; i < 8; ++i) l[i] = g[i];
        }
        {
            const float4* g = (const float4*)(Bsrc + (size_t)(n0 + bn) * DIM + kc + bks * 8);
            *(float4*)(&Bs[bn][bks * 8])     = g[0];
            *(float4*)(&Bs[bn][bks * 8 + 4]) = g[1];
        }
        __syncthreads();
#pragma unroll
        for (int kq = 0; kq < 8; ++kq) {
            float4 av[8], bv[8];
#pragma unroll
            for (int j = 0; j < 8; ++j)  av[j] = *(const float4*)(&As[oo + 32 * j][kq * 4]);
#pragma unroll
            for (int je = 0; je < 8; ++je) bv[je] = *(const float4*)(&Bs[ee + 8 * je][kq * 4]);
#pragma unroll
            for (int j = 0; j < 8; ++j)
#pragma unroll
                for (int je = 0; je < 8; ++je) {
                    acc[j][je] += av[j].x * bv[je].x;
                    acc[j][je] += av[j].y * bv[je].y;
                    acc[j][je] += av[j].z * bv[je].z;
                    acc[j][je] += av[j].w * bv[je].w;
                }
        }
        __syncthreads();
    }

    float bsum[8];
#pragma unroll
    for (int j = 0; j < 8; ++j) bsum[j] = ba[oo + 32 * j] + bo[oo + 32 * j];

    for (int c = 0; c < 4; ++c) {
#pragma unroll
        for (int jh = 0; jh < 2; ++jh) {
            int j = 2 * c + jh;
#pragma unroll
            for (int je = 0; je < 8; ++je)
                Cs[ee + 8 * je][oo + 32 * jh] = acc[j][je] + bsum[j];
        }
        __syncthreads();
        int ol = tid & 63, wv = tid >> 6;
        for (int r = wv; r < 64; r += 4)
            outb[(size_t)(n0 + r) * DIM + c * 64 + ol] = Cs[r][ol];
        __syncthreads();
    }
}

// ---------------- BN column stats (fp64 partials) ----------------
__global__ void k_colstat(const float* __restrict__ outb, double* __restrict__ psum,
                          double* __restrict__ psq) {
    int g = blockIdx.x, t = threadIdx.x;
    double s = 0.0, q = 0.0;
    const float* p = outb + (size_t)g * 256 * DIM + t;
    for (int r = 0; r < 256; ++r) { double v = (double)p[(size_t)r * DIM]; s += v; q += v * v; }
    psum[g * DIM + t] = s;
    psq[g * DIM + t] = q;
}

__global__ void k_bnparam(const double* __restrict__ psum, const double* __restrict__ psq,
                          const float* __restrict__ gamma, const float* __restrict__ beta,
                          float* __restrict__ scale, float* __restrict__ shift) {
    int t = threadIdx.x;
    double s = 0.0, q = 0.0;
    for (int g = 0; g < 32; ++g) { s += psum[g * DIM + t]; q += psq[g * DIM + t]; }
    double mean = s / (double)NODES;
    double var = q / (double)NODES - mean * mean;
    float sc = (float)((double)gamma[t] / sqrt(var + 1e-5));
    scale[t] = sc;
    shift[t] = (float)((double)beta[t] - mean * (double)sc);
}

// ---------------- affine + SELU + pooling score ----------------
__global__ void k_bnselu(float* __restrict__ outb, const float* __restrict__ scale,
                         const float* __restrict__ shift, const float* __restrict__ yw,
                         const float* __restrict__ yb, float* __restrict__ y) {
    int gw = (blockIdx.x * blockDim.x + threadIdx.x) >> 6;
    int lane = threadIdx.x & 63;
    if (gw >= NODES) return;
    float4 v  = *(const float4*)(outb + (size_t)gw * DIM + lane * 4);
    float4 sc = *(const float4*)(scale + lane * 4);
    float4 sh = *(const float4*)(shift + lane * 4);
    const float SL = 1.0507009873554805f, SA = 1.6732632423543772f;
    float4 o;
    o.x = v.x * sc.x + sh.x;
    o.y = v.y * sc.y + sh.y;
    o.z = v.z * sc.z + sh.z;
    o.w = v.w * sc.w + sh.w;
    o.x = (o.x > 0.f) ? SL * o.x : SL * SA * expm1f(o.x);
    o.y = (o.y > 0.f) ? SL * o.y : SL * SA * expm1f(o.y);
    o.z = (o.z > 0.f) ? SL * o.z : SL * SA * expm1f(o.z);
    o.w = (o.w > 0.f) ? SL * o.w : SL * SA * expm1f(o.w);
    *(float4*)(outb + (size_t)gw * DIM + lane * 4) = o;
    float4 w = *(const float4*)(yw + lane * 4);
    float z = o.x * w.x + o.y * w.y + o.z * w.z + o.w * w.w;
#pragma unroll
    for (int off = 32; off > 0; off >>= 1) z += __shfl_xor(z, off);
    if (lane == 0) y[gw] = 1.f / (1.f + expf(-(z + yb[0])));
}

// ---------------- per-batch bitonic top-k (val desc, idx asc — jax semantics) ----------------
__global__ void k_topk(const float* __restrict__ y, float* __restrict__ svals,
                       int* __restrict__ sidx) {
    __shared__ float v[1024];
    __shared__ int  id[1024];
    int b = blockIdx.x, t = threadIdx.x;   // 512 threads
    v[t] = y[b * 1024 + t];           id[t] = t;
    v[t + 512] = y[b * 1024 + t + 512]; id[t + 512] = t + 512;
    __syncthreads();
    for (int k = 2; k <= 1024; k <<= 1) {
        for (int j = k >> 1; j > 0; j >>= 1) {
            for (int i = t; i < 1024; i += 512) {
                int l = i ^ j;
                if (l > i) {
                    float vi = v[i], vl = v[l];
                    int ii = id[i], il = id[l];
                    bool precede = (vi > vl) || (vi == vl && ii < il);
                    bool dirDesc = ((i & k) == 0);
                    bool sw = dirDesc ? !precede : precede;
                    if (sw) { v[i] = vl; v[l] = vi; id[i] = il; id[l] = ii; }
                }
            }
            __syncthreads();
        }
    }
    if (t < 512) { svals[b * 512 + t] = v[t]; sidx[b * 512 + t] = id[t]; }
}

// ---------------- gather + gate ----------------
__global__ void k_gather(const float* __restrict__ outb, const float* __restrict__ svals,
                         const int* __restrict__ sidx, float* __restrict__ dout) {
    int gw = (blockIdx.x * blockDim.x + threadIdx.x) >> 6;
    int lane = threadIdx.x & 63;
    int b = gw >> 9, r = gw & 511;
    float val = svals[b * 512 + r];
    int idn = sidx[b * 512 + r];
    float4 vv = *(const float4*)(outb + (size_t)(b * 1024 + idn) * DIM + lane * 4);
    vv.x *= val; vv.y *= val; vv.z *= val; vv.w *= val;
    *(float4*)(dout + (size_t)(b * 512 + r) * DIM + lane * 4) = vv;
}

extern "C" void kernel_launch(void* const* d_in, const int* in_sizes, int n_in,
                              void* d_out, int out_size, void* d_ws, size_t ws_size,
                              hipStream_t stream) {
    const float* x     = (const float*)d_in[0];
    const int* edges   = (const int*)d_in[1];
    const float* att_w = (const float*)d_in[2];
    const float* att_b = (const float*)d_in[3];
    const float* amap  = (const float*)d_in[4];
    const float* pwa_w = (const float*)d_in[5];
    const float* pwa_b = (const float*)d_in[6];
    const float* pwo_w = (const float*)d_in[7];
    const float* pwo_b = (const float*)d_in[8];
    const float* gamma = (const float*)d_in[9];
    const float* beta  = (const float*)d_in[10];
    const float* yw    = (const float*)d_in[11];
    const float* yb    = (const float*)d_in[12];
    float* out = (float*)d_out;
    const int* src = edges;
    const int* dst = edges + NEDGE;

    char* ws = (char*)d_ws;
    size_t off = 0;
    auto alloc = [&](size_t b) { void* p = ws + off; off = (off + b + 255) & ~(size_t)255; return p; };
    float* alpha  = (float*)alloc((size_t)NEDGE * 4);
    int*   elist  = (int*)alloc((size_t)NEDGE * 4);
    float* agg    = (float*)alloc((size_t)NODES * DIM * 4);
    float* outb   = (float*)alloc((size_t)NODES * DIM * 4);
    int*   deg    = (int*)alloc(NODES * 4);
    int*   rowptr = (int*)alloc((NODES + 1) * 4);
    int*   cursor = (int*)alloc(NODES * 4);
    double* psum  = (double*)alloc(32 * DIM * 8);
    double* psq   = (double*)alloc(32 * DIM * 8);
    float* scale  = (float*)alloc(DIM * 4);
    float* shift  = (float*)alloc(DIM * 4);
    float* yv     = (float*)alloc(NODES * 4);
    float* svals  = (float*)alloc(8 * 512 * 4);
    int*   sidx   = (int*)alloc(8 * 512 * 4);
    u16*   w1     = (u16*)alloc((size_t)DIM * DIM * 2);
    u16*   w2     = (u16*)alloc((size_t)DIM * DIM * 2);
    u16*   w3     = (u16*)alloc((size_t)DIM * DIM * 2);

    k_wsplit<<<DIM * DIM / 256, 256, 0, stream>>>(att_w, w1, w2, w3);
    k_zero<<<NODES / 256, 256, 0, stream>>>(deg);
    k_deg<<<NEDGE / 256, 256, 0, stream>>>(dst, deg);
    k_scan<<<1, 256, 0, stream>>>(deg, rowptr, cursor);
    k_fill<<<NEDGE / 256, 256, 0, stream>>>(dst, cursor, elist);
    k_alpha_v3<<<NEDGE / 64, 256, 0, stream>>>(x, src, dst, w1, w2, w3, att_b, amap, alpha);
    k_aggregate<<<NODES / 4, 256, 0, stream>>>(x, src, alpha, rowptr, elist, agg);
    k_out<<<NODES / 64, 256, 0, stream>>>(agg, x, pwa_w, pwo_w, pwa_b, pwo_b, outb);
    k_colstat<<<32, 256, 0, stream>>>(outb, psum, psq);
    k_bnparam<<<1, 256, 0, stream>>>(psum, psq, gamma, beta, scale, shift);
    k_bnselu<<<NODES / 4, 256, 0, stream>>>(outb, scale, shift, yw, yb, yv);
    k_topk<<<8, 512, 0, stream>>>(yv, svals, sidx);
    k_gather<<<(8 * 512) / 4, 256, 0, stream>>>(outb, svals, sidx, out);
}

// Round 4
// 509.662 us; speedup vs baseline: 1.4168x; 1.0280x over previous
//
#include <hip/hip_runtime.h>
#include <math.h>

#define NODES 8192
#define NEDGE 262144
#define DIM 256

typedef float f32x16 __attribute__((ext_vector_type(16)));
typedef __bf16 bf16x8 __attribute__((ext_vector_type(8)));
typedef unsigned short u16;
typedef u16 u16x8 __attribute__((ext_vector_type(8)));

// ---------------- CSR build (dst-indexed) ----------------
__global__ void k_zero(int* __restrict__ deg) {
    int i = blockIdx.x * blockDim.x + threadIdx.x;
    if (i < NODES) deg[i] = 0;
}

__global__ void k_deg(const int* __restrict__ dst, int* __restrict__ deg) {
    int e = blockIdx.x * blockDim.x + threadIdx.x;
    if (e < NEDGE) atomicAdd(&deg[dst[e]], 1);
}

__global__ void k_scan(const int* __restrict__ deg, int* __restrict__ rowptr,
                       int* __restrict__ cursor) {
    __shared__ int part[256];
    int t = threadIdx.x;
    int base = t * 32;
    int local[32];
    int s = 0;
    for (int i = 0; i < 32; ++i) { local[i] = s; s += deg[base + i]; }
    part[t] = s;
    __syncthreads();
    for (int off = 1; off < 256; off <<= 1) {
        int v = (t >= off) ? part[t - off] : 0;
        __syncthreads();
        part[t] += v;
        __syncthreads();
    }
    int excl = (t == 0) ? 0 : part[t - 1];
    for (int i = 0; i < 32; ++i) {
        int v = excl + local[i];
        rowptr[base + i] = v;
        cursor[base + i] = v;
    }
    if (t == 255) rowptr[NODES] = part[255];
}

__global__ void k_fill(const int* __restrict__ dst, int* __restrict__ cursor,
                       int* __restrict__ elist) {
    int e = blockIdx.x * blockDim.x + threadIdx.x;
    if (e < NEDGE) {
        int pos = atomicAdd(&cursor[dst[e]], 1);
        elist[pos] = e;
    }
}

// ---------------- W -> MFMA-fragment-ordered 3-plane split ----------------
// wf[pl][mtg(8)][gks(16)][lane(64)][8] ; value = Wpl[mtg*32+(lane&31)][gks*16+(lane>>5)*8+j]
__global__ void k_wfrag(const float* __restrict__ W, u16* __restrict__ wf) {
    int t = blockIdx.x * blockDim.x + threadIdx.x;
    if (t >= 8 * 16 * 64) return;
    int lane = t & 63, gks = (t >> 6) & 15, mtg = t >> 10;
    int row = mtg * 32 + (lane & 31);
    int k0 = gks * 16 + (lane >> 5) * 8;
    const float* p = W + (size_t)row * DIM + k0;
    u16x8 v1, v2, v3;
#pragma unroll
    for (int j = 0; j < 8; ++j) {
        float f = p[j];
        unsigned uf = __float_as_uint(f);
        float r = f - __uint_as_float(uf & 0xFFFF0000u);
        unsigned ur = __float_as_uint(r);
        float r2 = r - __uint_as_float(ur & 0xFFFF0000u);
        unsigned ur2 = __float_as_uint(r2);
        v1[j] = (u16)(uf >> 16);
        v2[j] = (u16)(ur >> 16);
        v3[j] = (u16)(ur2 >> 16);
    }
    size_t base = ((size_t)(mtg * 16 + gks) * 64 + lane) * 8;
    const size_t plane = (size_t)8 * 16 * 64 * 8;
    *(u16x8*)(wf + 0 * plane + base) = v1;
    *(u16x8*)(wf + 1 * plane + base) = v2;
    *(u16x8*)(wf + 2 * plane + base) = v3;
}

// ---------------- alpha via 3-split bf16 MFMA 32x32x16, v4 ----------------
// Block: 256 thr / 4 waves, 64 edges, 256 outs. Wave w: rows [64w,64w+64)
// (2 M-tiles of 32) x 64 edges (2 N-tiles of 32). K=256 in 4 chunks of 64.
// A (W) from global in fragment order (coalesced 1KB/wave-load, L1-resident);
// B (p = x_i*x_j, 3-plane split) staged in LDS.
__global__ __launch_bounds__(256, 4) void k_alpha_v4(
    const float* __restrict__ x, const int* __restrict__ src, const int* __restrict__ dst,
    const u16* __restrict__ wf,
    const float* __restrict__ bias, const float* __restrict__ amap,
    float* __restrict__ alpha)
{
    __shared__ u16 p_lds[3][8][64][8];   // [plane][kblock(8k)][edge][8]
    __shared__ float red[4][64];
    const int tid = threadIdx.x;
    const int w = tid >> 6;
    const int lane = tid & 63;
    const int l31 = lane & 31;
    const int g2 = lane >> 5;
    const int e0 = blockIdx.x * 64;
    const size_t plane = (size_t)8 * 16 * 64 * 8;

    const int es = src[e0 + lane];
    const int ed = dst[e0 + lane];
    const float* xs = x + (size_t)es * DIM + w * 16;
    const float* xd = x + (size_t)ed * DIM + w * 16;

    f32x16 acc[2][2];
#pragma unroll
    for (int mt = 0; mt < 2; ++mt)
#pragma unroll
        for (int nt = 0; nt < 2; ++nt) acc[mt][nt] = (f32x16)0.f;

    const int PA[6] = {0, 0, 1, 0, 1, 2};
    const int PB[6] = {0, 1, 0, 2, 1, 0};

    for (int c = 0; c < 4; ++c) {
        if (c) __syncthreads();
        // ---- stage: thread = (edge lane, k-range [c*64 + w*16, +16)) ----
        {
            float4 s0 = *(const float4*)(xs + c * 64);
            float4 s1 = *(const float4*)(xs + c * 64 + 4);
            float4 s2 = *(const float4*)(xs + c * 64 + 8);
            float4 s3 = *(const float4*)(xs + c * 64 + 12);
            float4 d0 = *(const float4*)(xd + c * 64);
            float4 d1 = *(const float4*)(xd + c * 64 + 4);
            float4 d2 = *(const float4*)(xd + c * 64 + 8);
            float4 d3 = *(const float4*)(xd + c * 64 + 12);
            float pv[16];
            pv[0] = s0.x * d0.x; pv[1] = s0.y * d0.y; pv[2] = s0.z * d0.z; pv[3] = s0.w * d0.w;
            pv[4] = s1.x * d1.x; pv[5] = s1.y * d1.y; pv[6] = s1.z * d1.z; pv[7] = s1.w * d1.w;
            pv[8] = s2.x * d2.x; pv[9] = s2.y * d2.y; pv[10] = s2.z * d2.z; pv[11] = s2.w * d2.w;
            pv[12] = s3.x * d3.x; pv[13] = s3.y * d3.y; pv[14] = s3.z * d3.z; pv[15] = s3.w * d3.w;
#pragma unroll
            for (int q = 0; q < 2; ++q) {
                u16x8 v1, v2, v3;
#pragma unroll
                for (int i = 0; i < 8; ++i) {
                    float f = pv[q * 8 + i];
                    unsigned uf = __float_as_uint(f);
                    float r = f - __uint_as_float(uf & 0xFFFF0000u);
                    unsigned ur = __float_as_uint(r);
                    float r2 = r - __uint_as_float(ur & 0xFFFF0000u);
                    unsigned ur2 = __float_as_uint(r2);
                    v1[i] = (u16)(uf >> 16);
                    v2[i] = (u16)(ur >> 16);
                    v3[i] = (u16)(ur2 >> 16);
                }
                *(u16x8*)&p_lds[0][2 * w + q][lane][0] = v1;
                *(u16x8*)&p_lds[1][2 * w + q][lane][0] = v2;
                *(u16x8*)&p_lds[2][2 * w + q][lane][0] = v3;
            }
        }
        __syncthreads();

        // ---- 4 k-steps of 16 ----
#pragma unroll
        for (int ks = 0; ks < 4; ++ks) {
            const int gks = c * 4 + ks;
            bf16x8 bf[2][3];
#pragma unroll
            for (int nt = 0; nt < 2; ++nt)
#pragma unroll
                for (int pl = 0; pl < 3; ++pl)
                    bf[nt][pl] = *(const bf16x8*)(const void*)&p_lds[pl][2 * ks + g2][nt * 32 + l31][0];
#pragma unroll
            for (int mt = 0; mt < 2; ++mt) {
                bf16x8 af[3];
                size_t base = ((size_t)((2 * w + mt) * 16 + gks) * 64 + lane) * 8;
#pragma unroll
                for (int pl = 0; pl < 3; ++pl)
                    af[pl] = *(const bf16x8*)(const void*)(wf + pl * plane + base);
#pragma unroll
                for (int pr = 0; pr < 6; ++pr)
#pragma unroll
                    for (int nt = 0; nt < 2; ++nt)
                        acc[mt][nt] = __builtin_amdgcn_mfma_f32_32x32x16_bf16(
                            af[PA[pr]], bf[nt][PB[pr]], acc[mt][nt], 0, 0, 0);
            }
        }
    }

    // ---- epilogue: alpha[e] = sum_out amap*tanh(h+bias) ----
    float part[2] = {0.f, 0.f};
#pragma unroll
    for (int mt = 0; mt < 2; ++mt)
#pragma unroll
        for (int r = 0; r < 16; ++r) {
            int o = 64 * w + 32 * mt + (r & 3) + 8 * (r >> 2) + 4 * g2;
            float bo = bias[o], ao = amap[o];
#pragma unroll
            for (int nt = 0; nt < 2; ++nt)
                part[nt] += ao * tanhf(acc[mt][nt][r] + bo);
        }
#pragma unroll
    for (int nt = 0; nt < 2; ++nt) {
        float p = part[nt];
        p += __shfl_xor(p, 32);
        if (lane < 32) red[w][nt * 32 + lane] = p;
    }
    __syncthreads();
    if (tid < 64) alpha[e0 + tid] = red[0][tid] + red[1][tid] + red[2][tid] + red[3][tid];
}

// ---------------- per-node segment softmax + weighted aggregate ----------------
__global__ void k_aggregate(
    const float* __restrict__ x, const int* __restrict__ src,
    const float* __restrict__ alpha, const int* __restrict__ rowptr,
    const int* __restrict__ elist, float* __restrict__ agg)
{
    int gw = (blockIdx.x * blockDim.x + threadIdx.x) >> 6;
    int lane = threadIdx.x & 63;
    if (gw >= NODES) return;
    int start = rowptr[gw], end = rowptr[gw + 1];
    int deg = end - start;
    float m = -INFINITY;
    for (int i = lane; i < deg; i += 64) m = fmaxf(m, alpha[elist[start + i]]);
#pragma unroll
    for (int off = 32; off > 0; off >>= 1) m = fmaxf(m, __shfl_xor(m, off));
    float ssum = 0.f;
    for (int i = lane; i < deg; i += 64) ssum += expf(alpha[elist[start + i]] - m);
#pragma unroll
    for (int off = 32; off > 0; off >>= 1) ssum += __shfl_xor(ssum, off);
    float a0 = 0.f, a1 = 0.f, a2 = 0.f, a3 = 0.f;
    for (int i = 0; i < deg; ++i) {
        int e = elist[start + i];
        float w = expf(alpha[e] - m);
        const float4 v = *(const float4*)(x + (size_t)src[e] * DIM + lane * 4);
        a0 += w * v.x; a1 += w * v.y; a2 += w * v.z; a3 += w * v.w;
    }
    float inv = 1.f / (ssum + 1e-16f);
    float4 r; r.x = a0 * inv; r.y = a1 * inv; r.z = a2 * inv; r.w = a3 * inv;
    *(float4*)(agg + (size_t)gw * DIM + lane * 4) = r;
}

// ---------------- out = agg@pwa^T + x@pwo^T + biases ----------------
__global__ __launch_bounds__(256, 2) void k_out(
    const float* __restrict__ agg, const float* __restrict__ x,
    const float* __restrict__ Wa, const float* __restrict__ Wo,
    const float* __restrict__ ba, const float* __restrict__ bo,
    float* __restrict__ outb)
{
    __shared__ float As[256][36];
    __shared__ float Bs[64][36];
    __shared__ float Cs[64][68];
    const int tid = threadIdx.x;
    const int oo = tid >> 3, ee = tid & 7;
    const int n0 = blockIdx.x * 64;
    const int bn = tid >> 2, bks = tid & 3;

    float acc[8][8];
#pragma unroll
    for (int j = 0; j < 8; ++j)
#pragma unroll
        for (int je = 0; je < 8; ++je) acc[j][je] = 0.f;

    for (int cc = 0; cc < 16; ++cc) {
        const float* Wsrc = (cc < 8) ? Wa : Wo;
        const float* Bsrc = (cc < 8) ? agg : x;
        const int kc = (cc & 7) * 32;
        {
            const float4* g = (const float4*)(Wsrc + (size_t)tid * DIM + kc);
            float4* l = (float4*)(&As[tid][0]);
#pragma unroll
            for (int i = 0; i < 8; ++i) l[i] = g[i];
        }
        {
            const float4* g = (const float4*)(Bsrc + (size_t)(n0 + bn) * DIM + kc + bks * 8);
            *(float4*)(&Bs[bn][bks * 8])     = g[0];
            *(float4*)(&Bs[bn][bks * 8 + 4]) = g[1];
        }
        __syncthreads();
#pragma unroll
        for (int kq = 0; kq < 8; ++kq) {
            float4 av[8], bv[8];
#pragma unroll
            for (int j = 0; j < 8; ++j)  av[j] = *(const float4*)(&As[oo + 32 * j][kq * 4]);
#pragma unroll
            for (int je = 0; je < 8; ++je) bv[je] = *(const float4*)(&Bs[ee + 8 * je][kq * 4]);
#pragma unroll
            for (int j = 0; j < 8; ++j)
#pragma unroll
                for (int je = 0; je < 8; ++je) {
                    acc[j][je] += av[j].x * bv[je].x;
                    acc[j][je] += av[j].y * bv[je].y;
                    acc[j][je] += av[j].z * bv[je].z;
                    acc[j][je] += av[j].w * bv[je].w;
                }
        }
        __syncthreads();
    }

    float bsum[8];
#pragma unroll
    for (int j = 0; j < 8; ++j) bsum[j] = ba[oo + 32 * j] + bo[oo + 32 * j];

    for (int c = 0; c < 4; ++c) {
#pragma unroll
        for (int jh = 0; jh < 2; ++jh) {
            int j = 2 * c + jh;
#pragma unroll
            for (int je = 0; je < 8; ++je)
                Cs[ee + 8 * je][oo + 32 * jh] = acc[j][je] + bsum[j];
        }
        __syncthreads();
        int ol = tid & 63, wv = tid >> 6;
        for (int r = wv; r < 64; r += 4)
            outb[(size_t)(n0 + r) * DIM + c * 64 + ol] = Cs[r][ol];
        __syncthreads();
    }
}

// ---------------- BN column stats (fp64 partials) ----------------
__global__ void k_colstat(const float* __restrict__ outb, double* __restrict__ psum,
                          double* __restrict__ psq) {
    int g = blockIdx.x, t = threadIdx.x;
    double s = 0.0, q = 0.0;
    const float* p = outb + (size_t)g * 256 * DIM + t;
    for (int r = 0; r < 256; ++r) { double v = (double)p[(size_t)r * DIM]; s += v; q += v * v; }
    psum[g * DIM + t] = s;
    psq[g * DIM + t] = q;
}

__global__ void k_bnparam(const double* __restrict__ psum, const double* __restrict__ psq,
                          const float* __restrict__ gamma, const float* __restrict__ beta,
                          float* __restrict__ scale, float* __restrict__ shift) {
    int t = threadIdx.x;
    double s = 0.0, q = 0.0;
    for (int g = 0; g < 32; ++g) { s += psum[g * DIM + t]; q += psq[g * DIM + t]; }
    double mean = s / (double)NODES;
    double var = q / (double)NODES - mean * mean;
    float sc = (float)((double)gamma[t] / sqrt(var + 1e-5));
    scale[t] = sc;
    shift[t] = (float)((double)beta[t] - mean * (double)sc);
}

// ---------------- affine + SELU + pooling score ----------------
__global__ void k_bnselu(float* __restrict__ outb, const float* __restrict__ scale,
                         const float* __restrict__ shift, const float* __restrict__ yw,
                         const float* __restrict__ yb, float* __restrict__ y) {
    int gw = (blockIdx.x * blockDim.x + threadIdx.x) >> 6;
    int lane = threadIdx.x & 63;
    if (gw >= NODES) return;
    float4 v  = *(const float4*)(outb + (size_t)gw * DIM + lane * 4);
    float4 sc = *(const float4*)(scale + lane * 4);
    float4 sh = *(const float4*)(shift + lane * 4);
    const float SL = 1.0507009873554805f, SA = 1.6732632423543772f;
    float4 o;
    o.x = v.x * sc.x + sh.x;
    o.y = v.y * sc.y + sh.y;
    o.z = v.z * sc.z + sh.z;
    o.w = v.w * sc.w + sh.w;
    o.x = (o.x > 0.f) ? SL * o.x : SL * SA * expm1f(o.x);
    o.y = (o.y > 0.f) ? SL * o.y : SL * SA * expm1f(o.y);
    o.z = (o.z > 0.f) ? SL * o.z : SL * SA * expm1f(o.z);
    o.w = (o.w > 0.f) ? SL * o.w : SL * SA * expm1f(o.w);
    *(float4*)(outb + (size_t)gw * DIM + lane * 4) = o;
    float4 w = *(const float4*)(yw + lane * 4);
    float z = o.x * w.x + o.y * w.y + o.z * w.z + o.w * w.w;
#pragma unroll
    for (int off = 32; off > 0; off >>= 1) z += __shfl_xor(z, off);
    if (lane == 0) y[gw] = 1.f / (1.f + expf(-(z + yb[0])));
}

// ---------------- per-batch bitonic top-k (val desc, idx asc — jax semantics) ----------------
__global__ void k_topk(const float* __restrict__ y, float* __restrict__ svals,
                       int* __restrict__ sidx) {
    __shared__ float v[1024];
    __shared__ int  id[1024];
    int b = blockIdx.x, t = threadIdx.x;   // 512 threads
    v[t] = y[b * 1024 + t];           id[t] = t;
    v[t + 512] = y[b * 1024 + t + 512]; id[t + 512] = t + 512;
    __syncthreads();
    for (int k = 2; k <= 1024; k <<= 1) {
        for (int j = k >> 1; j > 0; j >>= 1) {
            for (int i = t; i < 1024; i += 512) {
                int l = i ^ j;
                if (l > i) {
                    float vi = v[i], vl = v[l];
                    int ii = id[i], il = id[l];
                    bool precede = (vi > vl) || (vi == vl && ii < il);
                    bool dirDesc = ((i & k) == 0);
                    bool sw = dirDesc ? !precede : precede;
                    if (sw) { v[i] = vl; v[l] = vi; id[i] = il; id[l] = ii; }
                }
            }
            __syncthreads();
        }
    }
    if (t < 512) { svals[b * 512 + t] = v[t]; sidx[b * 512 + t] = id[t]; }
}

// ---------------- gather + gate ----------------
__global__ void k_gather(const float* __restrict__ outb, const float* __restrict__ svals,
                         const int* __restrict__ sidx, float* __restrict__ dout) {
    int gw = (blockIdx.x * blockDim.x + threadIdx.x) >> 6;
    int lane = threadIdx.x & 63;
    int b = gw >> 9, r = gw & 511;
    float val = svals[b * 512 + r];
    int idn = sidx[b * 512 + r];
    float4 vv = *(const float4*)(outb + (size_t)(b * 1024 + idn) * DIM + lane * 4);
    vv.x *= val; vv.y *= val; vv.z *= val; vv.w *= val;
    *(float4*)(dout + (size_t)(b * 512 + r) * DIM + lane * 4) = vv;
}

extern "C" void kernel_launch(void* const* d_in, const int* in_sizes, int n_in,
                              void* d_out, int out_size, void* d_ws, size_t ws_size,
                              hipStream_t stream) {
    const float* x     = (const float*)d_in[0];
    const int* edges   = (const int*)d_in[1];
    const float* att_w = (const float*)d_in[2];
    const float* att_b = (const float*)d_in[3];
    const float* amap  = (const float*)d_in[4];
    const float* pwa_w = (const float*)d_in[5];
    const float* pwa_b = (const float*)d_in[6];
    const float* pwo_w = (const float*)d_in[7];
    const float* pwo_b = (const float*)d_in[8];
    const float* gamma = (const float*)d_in[9];
    const float* beta  = (const float*)d_in[10];
    const float* yw    = (const float*)d_in[11];
    const float* yb    = (const float*)d_in[12];
    float* out = (float*)d_out;
    const int* src = edges;
    const int* dst = edges + NEDGE;

    char* ws = (char*)d_ws;
    size_t off = 0;
    auto alloc = [&](size_t b) { void* p = ws + off; off = (off + b + 255) & ~(size_t)255; return p; };
    float* alpha  = (float*)alloc((size_t)NEDGE * 4);
    int*   elist  = (int*)alloc((size_t)NEDGE * 4);
    float* agg    = (float*)alloc((size_t)NODES * DIM * 4);
    float* outb   = (float*)alloc((size_t)NODES * DIM * 4);
    int*   deg    = (int*)alloc(NODES * 4);
    int*   rowptr = (int*)alloc((NODES + 1) * 4);
    int*   cursor = (int*)alloc(NODES * 4);
    double* psum  = (double*)alloc(32 * DIM * 8);
    double* psq   = (double*)alloc(32 * DIM * 8);
    float* scale  = (float*)alloc(DIM * 4);
    float* shift  = (float*)alloc(DIM * 4);
    float* yv     = (float*)alloc(NODES * 4);
    float* svals  = (float*)alloc(8 * 512 * 4);
    int*   sidx   = (int*)alloc(8 * 512 * 4);
    u16*   wf     = (u16*)alloc((size_t)3 * 8 * 16 * 64 * 8 * 2);

    k_wfrag<<<(8 * 16 * 64 + 255) / 256, 256, 0, stream>>>(att_w, wf);
    k_zero<<<NODES / 256, 256, 0, stream>>>(deg);
    k_deg<<<NEDGE / 256, 256, 0, stream>>>(dst, deg);
    k_scan<<<1, 256, 0, stream>>>(deg, rowptr, cursor);
    k_fill<<<NEDGE / 256, 256, 0, stream>>>(dst, cursor, elist);
    k_alpha_v4<<<NEDGE / 64, 256, 0, stream>>>(x, src, dst, wf, att_b, amap, alpha);
    k_aggregate<<<NODES / 4, 256, 0, stream>>>(x, src, alpha, rowptr, elist, agg);
    k_out<<<NODES / 64, 256, 0, stream>>>(agg, x, pwa_w, pwo_w, pwa_b, pwo_b, outb);
    k_colstat<<<32, 256, 0, stream>>>(outb, psum, psq);
    k_bnparam<<<1, 256, 0, stream>>>(psum, psq, gamma, beta, scale, shift);
    k_bnselu<<<NODES / 4, 256, 0, stream>>>(outb, scale, shift, yw, yb, yv);
    k_topk<<<8, 512, 0, stream>>>(yv, svals, sidx);
    k_gather<<<(8 * 512) / 4, 256, 0, stream>>>(outb, svals, sidx, out);
}

// Round 5
// 494.960 us; speedup vs baseline: 1.4589x; 1.0297x over previous
//
#include <hip/hip_runtime.h>
#include <math.h>

#define NODES 8192
#define NEDGE 262144
#define DIM 256

typedef float f32x16 __attribute__((ext_vector_type(16)));
typedef __bf16 bf16x8 __attribute__((ext_vector_type(8)));
typedef unsigned short u16;
typedef u16 u16x8 __attribute__((ext_vector_type(8)));

// ---------------- CSR build (dst-indexed) ----------------
__global__ void k_zero(int* __restrict__ deg) {
    int i = blockIdx.x * blockDim.x + threadIdx.x;
    if (i < NODES) deg[i] = 0;
}

__global__ void k_deg(const int* __restrict__ dst, int* __restrict__ deg) {
    int e = blockIdx.x * blockDim.x + threadIdx.x;
    if (e < NEDGE) atomicAdd(&deg[dst[e]], 1);
}

__global__ void k_scan(const int* __restrict__ deg, int* __restrict__ rowptr,
                       int* __restrict__ cursor) {
    __shared__ int part[256];
    int t = threadIdx.x;
    int base = t * 32;
    int local[32];
    int s = 0;
    for (int i = 0; i < 32; ++i) { local[i] = s; s += deg[base + i]; }
    part[t] = s;
    __syncthreads();
    for (int off = 1; off < 256; off <<= 1) {
        int v = (t >= off) ? part[t - off] : 0;
        __syncthreads();
        part[t] += v;
        __syncthreads();
    }
    int excl = (t == 0) ? 0 : part[t - 1];
    for (int i = 0; i < 32; ++i) {
        int v = excl + local[i];
        rowptr[base + i] = v;
        cursor[base + i] = v;
    }
    if (t == 255) rowptr[NODES] = part[255];
}

__global__ void k_fill(const int* __restrict__ dst, int* __restrict__ cursor,
                       int* __restrict__ elist) {
    int e = blockIdx.x * blockDim.x + threadIdx.x;
    if (e < NEDGE) {
        int pos = atomicAdd(&cursor[dst[e]], 1);
        elist[pos] = e;
    }
}

// ---------------- W -> per-(gks,wave) contiguous fragment order ----------------
// wf[((gks*4 + w)*6 + mt*3 + pl)*512 + lane*8 + j]
//   = Wpl[w*64 + mt*32 + (lane&31)][gks*16 + (lane>>5)*8 + j]
__global__ void k_wfrag(const float* __restrict__ W, u16* __restrict__ wf) {
    int t = blockIdx.x * blockDim.x + threadIdx.x;
    if (t >= 16 * 4 * 2 * 64) return;
    int lane = t & 63;
    int mt = (t >> 6) & 1;
    int w = (t >> 7) & 3;
    int gks = t >> 9;
    int row = w * 64 + mt * 32 + (lane & 31);
    int k0 = gks * 16 + (lane >> 5) * 8;
    const float* p = W + (size_t)row * DIM + k0;
    u16x8 v1, v2, v3;
#pragma unroll
    for (int j = 0; j < 8; ++j) {
        float f = p[j];
        unsigned uf = __float_as_uint(f);
        float r = f - __uint_as_float(uf & 0xFFFF0000u);
        unsigned ur = __float_as_uint(r);
        float r2 = r - __uint_as_float(ur & 0xFFFF0000u);
        unsigned ur2 = __float_as_uint(r2);
        v1[j] = (u16)(uf >> 16);
        v2[j] = (u16)(ur >> 16);
        v3[j] = (u16)(ur2 >> 16);
    }
    size_t base = ((size_t)(gks * 4 + w) * 6 + mt * 3) * 512 + lane * 8;
    *(u16x8*)(wf + base)       = v1;
    *(u16x8*)(wf + base + 512) = v2;
    *(u16x8*)(wf + base + 1024) = v3;
}

// ---------------- alpha via 3-split bf16 MFMA 32x32x16, v5 ----------------
// Block: 256 thr / 4 waves, 128 edges, 256 outs. Wave w: rows [64w,64w+64)
// (mt=2) x 128 edges (nt=4). K=256 in 4 chunks of 64 staged in LDS.
// A (wf) streamed from global, ping-pong prefetched one k-step ahead.
__global__ __launch_bounds__(256, 2) void k_alpha_v5(
    const float* __restrict__ x, const int* __restrict__ src, const int* __restrict__ dst,
    const u16* __restrict__ wf,
    const float* __restrict__ bias, const float* __restrict__ amap,
    float* __restrict__ alpha)
{
    __shared__ u16 p_lds[3][8][128][8];   // [plane][kb(8k)][edge][8] = 48 KB
    __shared__ float red[4][128];
    const int tid = threadIdx.x;
    const int w = tid >> 6;
    const int lane = tid & 63;
    const int l31 = lane & 31;
    const int g2 = lane >> 5;
    const int e0 = blockIdx.x * 128;

    // staging role: edge = tid&127, k-half (32 floats) = tid>>7
    const int se = tid & 127;
    const int kh = tid >> 7;
    const int es = src[e0 + se];
    const int ed = dst[e0 + se];
    const float* xs = x + (size_t)es * DIM + kh * 32;
    const float* xd = x + (size_t)ed * DIM + kh * 32;

    f32x16 acc[2][4];
#pragma unroll
    for (int mt = 0; mt < 2; ++mt)
#pragma unroll
        for (int nt = 0; nt < 4; ++nt) acc[mt][nt] = (f32x16)0.f;

    const int PA[6] = {0, 0, 1, 0, 1, 2};
    const int PB[6] = {0, 1, 0, 2, 1, 0};

    bf16x8 afa[2][3], afb[2][3];
    // preload af for gks=0 into afa
    {
        size_t pb = ((size_t)(0 * 4 + w) * 6) * 512 + lane * 8;
#pragma unroll
        for (int mt = 0; mt < 2; ++mt)
#pragma unroll
            for (int pl = 0; pl < 3; ++pl)
                afa[mt][pl] = *(const bf16x8*)(const void*)(wf + pb + (mt * 3 + pl) * 512);
    }

#define BODY(AF_USE, AF_PF, KS) { \
    const int gks = c * 4 + (KS); \
    if (gks < 15) { \
        size_t pb = ((size_t)((gks + 1) * 4 + w) * 6) * 512 + lane * 8; \
        _Pragma("unroll") for (int mt = 0; mt < 2; ++mt) \
        _Pragma("unroll") for (int pl = 0; pl < 3; ++pl) \
            AF_PF[mt][pl] = *(const bf16x8*)(const void*)(wf + pb + (mt * 3 + pl) * 512); \
    } \
    bf16x8 bfr[4][3]; \
    _Pragma("unroll") for (int nt = 0; nt < 4; ++nt) \
    _Pragma("unroll") for (int pl = 0; pl < 3; ++pl) \
        bfr[nt][pl] = *(const bf16x8*)(const void*)&p_lds[pl][2 * (KS) + g2][nt * 32 + l31][0]; \
    _Pragma("unroll") for (int pr = 0; pr < 6; ++pr) \
    _Pragma("unroll") for (int mt = 0; mt < 2; ++mt) \
    _Pragma("unroll") for (int nt = 0; nt < 4; ++nt) \
        acc[mt][nt] = __builtin_amdgcn_mfma_f32_32x32x16_bf16( \
            AF_USE[mt][PA[pr]], bfr[nt][PB[pr]], acc[mt][nt], 0, 0, 0); \
}

    for (int c = 0; c < 4; ++c) {
        if (c) __syncthreads();
        // ---- stage chunk c: 128 edges x 64 k, 3-plane split ----
#pragma unroll
        for (int h = 0; h < 2; ++h) {
            float4 s[4], d[4];
#pragma unroll
            for (int j = 0; j < 4; ++j) {
                s[j] = *(const float4*)(xs + c * 64 + h * 16 + j * 4);
                d[j] = *(const float4*)(xd + c * 64 + h * 16 + j * 4);
            }
#pragma unroll
            for (int q = 0; q < 2; ++q) {
                u16x8 v1, v2, v3;
#pragma unroll
                for (int i = 0; i < 8; ++i) {
                    int idx = q * 8 + i;
                    float f = ((const float*)s)[idx] * ((const float*)d)[idx];
                    unsigned uf = __float_as_uint(f);
                    float r = f - __uint_as_float(uf & 0xFFFF0000u);
                    unsigned ur = __float_as_uint(r);
                    float r2 = r - __uint_as_float(ur & 0xFFFF0000u);
                    unsigned ur2 = __float_as_uint(r2);
                    v1[i] = (u16)(uf >> 16);
                    v2[i] = (u16)(ur >> 16);
                    v3[i] = (u16)(ur2 >> 16);
                }
                int kb = kh * 4 + h * 2 + q;
                *(u16x8*)&p_lds[0][kb][se][0] = v1;
                *(u16x8*)&p_lds[1][kb][se][0] = v2;
                *(u16x8*)&p_lds[2][kb][se][0] = v3;
            }
        }
        __syncthreads();

        BODY(afa, afb, 0)
        BODY(afb, afa, 1)
        BODY(afa, afb, 2)
        BODY(afb, afa, 3)
    }
#undef BODY

    // ---- epilogue: alpha[e] = sum_out amap*tanh(h+bias) ----
    float part[4] = {0.f, 0.f, 0.f, 0.f};
#pragma unroll
    for (int mt = 0; mt < 2; ++mt)
#pragma unroll
        for (int r = 0; r < 16; ++r) {
            int o = 64 * w + 32 * mt + (r & 3) + 8 * (r >> 2) + 4 * g2;
            float bo = bias[o], ao = amap[o];
#pragma unroll
            for (int nt = 0; nt < 4; ++nt)
                part[nt] += ao * tanhf(acc[mt][nt][r] + bo);
        }
#pragma unroll
    for (int nt = 0; nt < 4; ++nt) {
        float p = part[nt];
        p += __shfl_xor(p, 32);
        if (lane < 32) red[w][nt * 32 + lane] = p;
    }
    __syncthreads();
    if (tid < 128) alpha[e0 + tid] = red[0][tid] + red[1][tid] + red[2][tid] + red[3][tid];
}

// ---------------- per-node segment softmax + weighted aggregate ----------------
__global__ void k_aggregate(
    const float* __restrict__ x, const int* __restrict__ src,
    const float* __restrict__ alpha, const int* __restrict__ rowptr,
    const int* __restrict__ elist, float* __restrict__ agg)
{
    int gw = (blockIdx.x * blockDim.x + threadIdx.x) >> 6;
    int lane = threadIdx.x & 63;
    if (gw >= NODES) return;
    int start = rowptr[gw], end = rowptr[gw + 1];
    int deg = end - start;
    float m = -INFINITY;
    for (int i = lane; i < deg; i += 64) m = fmaxf(m, alpha[elist[start + i]]);
#pragma unroll
    for (int off = 32; off > 0; off >>= 1) m = fmaxf(m, __shfl_xor(m, off));
    float ssum = 0.f;
    for (int i = lane; i < deg; i += 64) ssum += expf(alpha[elist[start + i]] - m);
#pragma unroll
    for (int off = 32; off > 0; off >>= 1) ssum += __shfl_xor(ssum, off);
    float a0 = 0.f, a1 = 0.f, a2 = 0.f, a3 = 0.f;
    for (int i = 0; i < deg; ++i) {
        int e = elist[start + i];
        float w = expf(alpha[e] - m);
        const float4 v = *(const float4*)(x + (size_t)src[e] * DIM + lane * 4);
        a0 += w * v.x; a1 += w * v.y; a2 += w * v.z; a3 += w * v.w;
    }
    float inv = 1.f / (ssum + 1e-16f);
    float4 r; r.x = a0 * inv; r.y = a1 * inv; r.z = a2 * inv; r.w = a3 * inv;
    *(float4*)(agg + (size_t)gw * DIM + lane * 4) = r;
}

// ---------------- out = agg@pwa^T + x@pwo^T + biases ----------------
__global__ __launch_bounds__(256, 2) void k_out(
    const float* __restrict__ agg, const float* __restrict__ x,
    const float* __restrict__ Wa, const float* __restrict__ Wo,
    const float* __restrict__ ba, const float* __restrict__ bo,
    float* __restrict__ outb)
{
    __shared__ float As[256][36];
    __shared__ float Bs[64][36];
    __shared__ float Cs[64][68];
    const int tid = threadIdx.x;
    const int oo = tid >> 3, ee = tid & 7;
    const int n0 = blockIdx.x * 64;
    const int bn = tid >> 2, bks = tid & 3;

    float acc[8][8];
#pragma unroll
    for (int j = 0; j < 8; ++j)
#pragma unroll
        for (int je = 0; je < 8; ++je) acc[j][je] = 0.f;

    for (int cc = 0; cc < 16; ++cc) {
        const float* Wsrc = (cc < 8) ? Wa : Wo;
        const float* Bsrc = (cc < 8) ? agg : x;
        const int kc = (cc & 7) * 32;
        {
            const float4* g = (const float4*)(Wsrc + (size_t)tid * DIM + kc);
            float4* l = (float4*)(&As[tid][0]);
#pragma unroll
            for (int i = 0; i < 8; ++i) l[i] = g[i];
        }
        {
            const float4* g = (const float4*)(Bsrc + (size_t)(n0 + bn) * DIM + kc + bks * 8);
            *(float4*)(&Bs[bn][bks * 8])     = g[0];
            *(float4*)(&Bs[bn][bks * 8 + 4]) = g[1];
        }
        __syncthreads();
#pragma unroll
        for (int kq = 0; kq < 8; ++kq) {
            float4 av[8], bv[8];
#pragma unroll
            for (int j = 0; j < 8; ++j)  av[j] = *(const float4*)(&As[oo + 32 * j][kq * 4]);
#pragma unroll
            for (int je = 0; je < 8; ++je) bv[je] = *(const float4*)(&Bs[ee + 8 * je][kq * 4]);
#pragma unroll
            for (int j = 0; j < 8; ++j)
#pragma unroll
                for (int je = 0; je < 8; ++je) {
                    acc[j][je] += av[j].x * bv[je].x;
                    acc[j][je] += av[j].y * bv[je].y;
                    acc[j][je] += av[j].z * bv[je].z;
                    acc[j][je] += av[j].w * bv[je].w;
                }
        }
        __syncthreads();
    }

    float bsum[8];
#pragma unroll
    for (int j = 0; j < 8; ++j) bsum[j] = ba[oo + 32 * j] + bo[oo + 32 * j];

    for (int c = 0; c < 4; ++c) {
#pragma unroll
        for (int jh = 0; jh < 2; ++jh) {
            int j = 2 * c + jh;
#pragma unroll
            for (int je = 0; je < 8; ++je)
                Cs[ee + 8 * je][oo + 32 * jh] = acc[j][je] + bsum[j];
        }
        __syncthreads();
        int ol = tid & 63, wv = tid >> 6;
        for (int r = wv; r < 64; r += 4)
            outb[(size_t)(n0 + r) * DIM + c * 64 + ol] = Cs[r][ol];
        __syncthreads();
    }
}

// ---------------- BN column stats (fp64 partials) ----------------
__global__ void k_colstat(const float* __restrict__ outb, double* __restrict__ psum,
                          double* __restrict__ psq) {
    int g = blockIdx.x, t = threadIdx.x;
    double s = 0.0, q = 0.0;
    const float* p = outb + (size_t)g * 256 * DIM + t;
    for (int r = 0; r < 256; ++r) { double v = (double)p[(size_t)r * DIM]; s += v; q += v * v; }
    psum[g * DIM + t] = s;
    psq[g * DIM + t] = q;
}

__global__ void k_bnparam(const double* __restrict__ psum, const double* __restrict__ psq,
                          const float* __restrict__ gamma, const float* __restrict__ beta,
                          float* __restrict__ scale, float* __restrict__ shift) {
    int t = threadIdx.x;
    double s = 0.0, q = 0.0;
    for (int g = 0; g < 32; ++g) { s += psum[g * DIM + t]; q += psq[g * DIM + t]; }
    double mean = s / (double)NODES;
    double var = q / (double)NODES - mean * mean;
    float sc = (float)((double)gamma[t] / sqrt(var + 1e-5));
    scale[t] = sc;
    shift[t] = (float)((double)beta[t] - mean * (double)sc);
}

// ---------------- affine + SELU + pooling score ----------------
__global__ void k_bnselu(float* __restrict__ outb, const float* __restrict__ scale,
                         const float* __restrict__ shift, const float* __restrict__ yw,
                         const float* __restrict__ yb, float* __restrict__ y) {
    int gw = (blockIdx.x * blockDim.x + threadIdx.x) >> 6;
    int lane = threadIdx.x & 63;
    if (gw >= NODES) return;
    float4 v  = *(const float4*)(outb + (size_t)gw * DIM + lane * 4);
    float4 sc = *(const float4*)(scale + lane * 4);
    float4 sh = *(const float4*)(shift + lane * 4);
    const float SL = 1.0507009873554805f, SA = 1.6732632423543772f;
    float4 o;
    o.x = v.x * sc.x + sh.x;
    o.y = v.y * sc.y + sh.y;
    o.z = v.z * sc.z + sh.z;
    o.w = v.w * sc.w + sh.w;
    o.x = (o.x > 0.f) ? SL * o.x : SL * SA * expm1f(o.x);
    o.y = (o.y > 0.f) ? SL * o.y : SL * SA * expm1f(o.y);
    o.z = (o.z > 0.f) ? SL * o.z : SL * SA * expm1f(o.z);
    o.w = (o.w > 0.f) ? SL * o.w : SL * SA * expm1f(o.w);
    *(float4*)(outb + (size_t)gw * DIM + lane * 4) = o;
    float4 w = *(const float4*)(yw + lane * 4);
    float z = o.x * w.x + o.y * w.y + o.z * w.z + o.w * w.w;
#pragma unroll
    for (int off = 32; off > 0; off >>= 1) z += __shfl_xor(z, off);
    if (lane == 0) y[gw] = 1.f / (1.f + expf(-(z + yb[0])));
}

// ---------------- per-batch bitonic top-k (val desc, idx asc — jax semantics) ----------------
__global__ void k_topk(const float* __restrict__ y, float* __restrict__ svals,
                       int* __restrict__ sidx) {
    __shared__ float v[1024];
    __shared__ int  id[1024];
    int b = blockIdx.x, t = threadIdx.x;   // 512 threads
    v[t] = y[b * 1024 + t];           id[t] = t;
    v[t + 512] = y[b * 1024 + t + 512]; id[t + 512] = t + 512;
    __syncthreads();
    for (int k = 2; k <= 1024; k <<= 1) {
        for (int j = k >> 1; j > 0; j >>= 1) {
            for (int i = t; i < 1024; i += 512) {
                int l = i ^ j;
                if (l > i) {
                    float vi = v[i], vl = v[l];
                    int ii = id[i], il = id[l];
                    bool precede = (vi > vl) || (vi == vl && ii < il);
                    bool dirDesc = ((i & k) == 0);
                    bool sw = dirDesc ? !precede : precede;
                    if (sw) { v[i] = vl; v[l] = vi; id[i] = il; id[l] = ii; }
                }
            }
            __syncthreads();
        }
    }
    if (t < 512) { svals[b * 512 + t] = v[t]; sidx[b * 512 + t] = id[t]; }
}

// ---------------- gather + gate ----------------
__global__ void k_gather(const float* __restrict__ outb, const float* __restrict__ svals,
                         const int* __restrict__ sidx, float* __restrict__ dout) {
    int gw = (blockIdx.x * blockDim.x + threadIdx.x) >> 6;
    int lane = threadIdx.x & 63;
    int b = gw >> 9, r = gw & 511;
    float val = svals[b * 512 + r];
    int idn = sidx[b * 512 + r];
    float4 vv = *(const float4*)(outb + (size_t)(b * 1024 + idn) * DIM + lane * 4);
    vv.x *= val; vv.y *= val; vv.z *= val; vv.w *= val;
    *(float4*)(dout + (size_t)(b * 512 + r) * DIM + lane * 4) = vv;
}

extern "C" void kernel_launch(void* const* d_in, const int* in_sizes, int n_in,
                              void* d_out, int out_size, void* d_ws, size_t ws_size,
                              hipStream_t stream) {
    const float* x     = (const float*)d_in[0];
    const int* edges   = (const int*)d_in[1];
    const float* att_w = (const float*)d_in[2];
    const float* att_b = (const float*)d_in[3];
    const float* amap  = (const float*)d_in[4];
    const float* pwa_w = (const float*)d_in[5];
    const float* pwa_b = (const float*)d_in[6];
    const float* pwo_w = (const float*)d_in[7];
    const float* pwo_b = (const float*)d_in[8];
    const float* gamma = (const float*)d_in[9];
    const float* beta  = (const float*)d_in[10];
    const float* yw    = (const float*)d_in[11];
    const float* yb    = (const float*)d_in[12];
    float* out = (float*)d_out;
    const int* src = edges;
    const int* dst = edges + NEDGE;

    char* ws = (char*)d_ws;
    size_t off = 0;
    auto alloc = [&](size_t b) { void* p = ws + off; off = (off + b + 255) & ~(size_t)255; return p; };
    float* alpha  = (float*)alloc((size_t)NEDGE * 4);
    int*   elist  = (int*)alloc((size_t)NEDGE * 4);
    float* agg    = (float*)alloc((size_t)NODES * DIM * 4);
    float* outb   = (float*)alloc((size_t)NODES * DIM * 4);
    int*   deg    = (int*)alloc(NODES * 4);
    int*   rowptr = (int*)alloc((NODES + 1) * 4);
    int*   cursor = (int*)alloc(NODES * 4);
    double* psum  = (double*)alloc(32 * DIM * 8);
    double* psq   = (double*)alloc(32 * DIM * 8);
    float* scale  = (float*)alloc(DIM * 4);
    float* shift  = (float*)alloc(DIM * 4);
    float* yv     = (float*)alloc(NODES * 4);
    float* svals  = (float*)alloc(8 * 512 * 4);
    int*   sidx   = (int*)alloc(8 * 512 * 4);
    u16*   wf     = (u16*)alloc((size_t)16 * 4 * 6 * 512 * 2);

    k_wfrag<<<32, 256, 0, stream>>>(att_w, wf);
    k_zero<<<NODES / 256, 256, 0, stream>>>(deg);
    k_deg<<<NEDGE / 256, 256, 0, stream>>>(dst, deg);
    k_scan<<<1, 256, 0, stream>>>(deg, rowptr, cursor);
    k_fill<<<NEDGE / 256, 256, 0, stream>>>(dst, cursor, elist);
    k_alpha_v5<<<NEDGE / 128, 256, 0, stream>>>(x, src, dst, wf, att_b, amap, alpha);
    k_aggregate<<<NODES / 4, 256, 0, stream>>>(x, src, alpha, rowptr, elist, agg);
    k_out<<<NODES / 64, 256, 0, stream>>>(agg, x, pwa_w, pwo_w, pwa_b, pwo_b, outb);
    k_colstat<<<32, 256, 0, stream>>>(outb, psum, psq);
    k_bnparam<<<1, 256, 0, stream>>>(psum, psq, gamma, beta, scale, shift);
    k_bnselu<<<NODES / 4, 256, 0, stream>>>(outb, scale, shift, yw, yb, yv);
    k_topk<<<8, 512, 0, stream>>>(yv, svals, sidx);
    k_gather<<<(8 * 512) / 4, 256, 0, stream>>>(outb, svals, sidx, out);
}

// Round 6
// 410.978 us; speedup vs baseline: 1.7570x; 1.2043x over previous
//
#include <hip/hip_runtime.h>
#include <math.h>

#define NODES 8192
#define NEDGE 262144
#define DIM 256

typedef float f32x16 __attribute__((ext_vector_type(16)));
typedef __bf16 bf16x8 __attribute__((ext_vector_type(8)));
typedef unsigned short u16;
typedef u16 u16x8 __attribute__((ext_vector_type(8)));

__device__ __forceinline__ float fast_tanh(float x) {
    float t = __expf(2.f * x);                       // v_exp + mul
    return 1.f - 2.f * __builtin_amdgcn_rcpf(t + 1.f); // ~1ulp rcp; inf->1, 0->-1
}

// ---------------- CSR build (dst-indexed) ----------------
__global__ void k_zero(int* __restrict__ deg) {
    int i = blockIdx.x * blockDim.x + threadIdx.x;
    if (i < NODES) deg[i] = 0;
}

__global__ void k_deg(const int* __restrict__ dst, int* __restrict__ deg) {
    int e = blockIdx.x * blockDim.x + threadIdx.x;
    if (e < NEDGE) atomicAdd(&deg[dst[e]], 1);
}

__global__ void k_scan(const int* __restrict__ deg, int* __restrict__ rowptr,
                       int* __restrict__ cursor) {
    __shared__ int part[256];
    int t = threadIdx.x;
    int base = t * 32;
    int local[32];
    int s = 0;
    for (int i = 0; i < 32; ++i) { local[i] = s; s += deg[base + i]; }
    part[t] = s;
    __syncthreads();
    for (int off = 1; off < 256; off <<= 1) {
        int v = (t >= off) ? part[t - off] : 0;
        __syncthreads();
        part[t] += v;
        __syncthreads();
    }
    int excl = (t == 0) ? 0 : part[t - 1];
    for (int i = 0; i < 32; ++i) {
        int v = excl + local[i];
        rowptr[base + i] = v;
        cursor[base + i] = v;
    }
    if (t == 255) rowptr[NODES] = part[255];
}

__global__ void k_fill(const int* __restrict__ dst, int* __restrict__ cursor,
                       int* __restrict__ elist) {
    int e = blockIdx.x * blockDim.x + threadIdx.x;
    if (e < NEDGE) {
        int pos = atomicAdd(&cursor[dst[e]], 1);
        elist[pos] = e;
    }
}

// ---------------- W -> per-(gks,wave) contiguous fragment order ----------------
// wf[((gks*4 + w)*6 + mt*3 + pl)*512 + lane*8 + j]
//   = Wpl[w*64 + mt*32 + (lane&31)][gks*16 + (lane>>5)*8 + j]
__global__ void k_wfrag(const float* __restrict__ W, u16* __restrict__ wf) {
    int t = blockIdx.x * blockDim.x + threadIdx.x;
    if (t >= 16 * 4 * 2 * 64) return;
    int lane = t & 63;
    int mt = (t >> 6) & 1;
    int w = (t >> 7) & 3;
    int gks = t >> 9;
    int row = w * 64 + mt * 32 + (lane & 31);
    int k0 = gks * 16 + (lane >> 5) * 8;
    const float* p = W + (size_t)row * DIM + k0;
    u16x8 v1, v2, v3;
#pragma unroll
    for (int j = 0; j < 8; ++j) {
        float f = p[j];
        unsigned uf = __float_as_uint(f);
        float r = f - __uint_as_float(uf & 0xFFFF0000u);
        unsigned ur = __float_as_uint(r);
        float r2 = r - __uint_as_float(ur & 0xFFFF0000u);
        unsigned ur2 = __float_as_uint(r2);
        v1[j] = (u16)(uf >> 16);
        v2[j] = (u16)(ur >> 16);
        v3[j] = (u16)(ur2 >> 16);
    }
    size_t base = ((size_t)(gks * 4 + w) * 6 + mt * 3) * 512 + lane * 8;
    *(u16x8*)(wf + base)        = v1;
    *(u16x8*)(wf + base + 512)  = v2;
    *(u16x8*)(wf + base + 1024) = v3;
}

// ---------------- alpha via 3-split bf16 MFMA 32x32x16, v6 ----------------
// Block: 256 thr / 4 waves, 64 edges, 256 outs. Wave w: rows [64w,64w+64)
// (mt=2) x 64 edges (nt=2). K=256 in 4 chunks of 64.
// p_lds double-buffered; A ping-pong prefetched; everything statically unrolled.
// Register budget: acc 64 + afA/afB 48 + bfr 24 + staging 32 + addr ~20 < 256.
__global__ __launch_bounds__(256, 2) void k_alpha_v6(
    const float* __restrict__ x, const int* __restrict__ src, const int* __restrict__ dst,
    const u16* __restrict__ wf,
    const float* __restrict__ bias, const float* __restrict__ amap,
    float* __restrict__ alpha)
{
    __shared__ u16 p_lds[2][3][8][64][8];   // [buf][plane][kb(8k)][edge][8] = 48 KB
    __shared__ float red[4][64];
    const int tid = threadIdx.x;
    const int w = tid >> 6;
    const int lane = tid & 63;
    const int l31 = lane & 31;
    const int g2 = lane >> 5;
    const int e0 = blockIdx.x * 64;

    // staging role: edge = tid&63, 16-k slice within chunk = tid>>6
    const int se = tid & 63;
    const int kq = tid >> 6;
    const int es = src[e0 + se];
    const int ed = dst[e0 + se];
    const float* xs = x + (size_t)es * DIM + kq * 16;
    const float* xd = x + (size_t)ed * DIM + kq * 16;

    f32x16 acc[2][2];
#pragma unroll
    for (int mt = 0; mt < 2; ++mt)
#pragma unroll
        for (int nt = 0; nt < 2; ++nt) acc[mt][nt] = (f32x16)0.f;

    const int PA[6] = {0, 0, 1, 0, 1, 2};
    const int PB[6] = {0, 1, 0, 2, 1, 0};

    bf16x8 afA[2][3], afB[2][3];
    float4 sv[4], dv[4];

#define STAGE_LOAD(C) { \
    _Pragma("unroll") for (int j = 0; j < 4; ++j) { \
        sv[j] = *(const float4*)(xs + (C) * 64 + j * 4); \
        dv[j] = *(const float4*)(xd + (C) * 64 + j * 4); } }

#define STAGE_WRITE(C) { \
    _Pragma("unroll") for (int q = 0; q < 2; ++q) { \
        u16x8 v1, v2, v3; \
        _Pragma("unroll") for (int i = 0; i < 8; ++i) { \
            int idx = q * 8 + i; \
            float f = ((const float*)sv)[idx] * ((const float*)dv)[idx]; \
            unsigned uf = __float_as_uint(f); \
            float r = f - __uint_as_float(uf & 0xFFFF0000u); \
            unsigned ur = __float_as_uint(r); \
            float r2 = r - __uint_as_float(ur & 0xFFFF0000u); \
            unsigned ur2 = __float_as_uint(r2); \
            v1[i] = (u16)(uf >> 16); \
            v2[i] = (u16)(ur >> 16); \
            v3[i] = (u16)(ur2 >> 16); } \
        const int kb = kq * 2 + q; \
        *(u16x8*)&p_lds[(C) & 1][0][kb][se][0] = v1; \
        *(u16x8*)&p_lds[(C) & 1][1][kb][se][0] = v2; \
        *(u16x8*)&p_lds[(C) & 1][2][kb][se][0] = v3; } }

#define PREFA(DST, GKS) { \
    const u16* pb = wf + ((size_t)((GKS) * 4 + w) * 6) * 512 + lane * 8; \
    _Pragma("unroll") for (int mt = 0; mt < 2; ++mt) \
    _Pragma("unroll") for (int pl = 0; pl < 3; ++pl) \
        DST[mt][pl] = *(const bf16x8*)(const void*)(pb + (mt * 3 + pl) * 512); }

#define KSTEP(C, KS) { \
    const int gks_ = (C) * 4 + (KS); \
    if (gks_ + 1 < 16) { \
        if (gks_ & 1) { PREFA(afA, gks_ + 1) } else { PREFA(afB, gks_ + 1) } \
    } \
    bf16x8 bfr[2][3]; \
    _Pragma("unroll") for (int nt = 0; nt < 2; ++nt) \
    _Pragma("unroll") for (int pl = 0; pl < 3; ++pl) \
        bfr[nt][pl] = *(const bf16x8*)(const void*)&p_lds[(C) & 1][pl][2 * (KS) + g2][nt * 32 + l31][0]; \
    _Pragma("unroll") for (int pr = 0; pr < 6; ++pr) \
    _Pragma("unroll") for (int mt = 0; mt < 2; ++mt) \
    _Pragma("unroll") for (int nt = 0; nt < 2; ++nt) \
        acc[mt][nt] = __builtin_amdgcn_mfma_f32_32x32x16_bf16( \
            (gks_ & 1) ? afB[mt][PA[pr]] : afA[mt][PA[pr]], \
            bfr[nt][PB[pr]], acc[mt][nt], 0, 0, 0); }

    // prologue: stage chunk 0, preload A step 0
    STAGE_LOAD(0)
    PREFA(afA, 0)
    STAGE_WRITE(0)
    __syncthreads();

#pragma unroll
    for (int c = 0; c < 4; ++c) {
        if (c < 3) STAGE_LOAD(c + 1)
        KSTEP(c, 0)
        KSTEP(c, 1)
        if (c < 3) STAGE_WRITE(c + 1)
        KSTEP(c, 2)
        KSTEP(c, 3)
        __syncthreads();
    }
#undef STAGE_LOAD
#undef STAGE_WRITE
#undef PREFA
#undef KSTEP

    // ---- epilogue: alpha[e] = sum_out amap*tanh(h+bias) ----
    float part[2] = {0.f, 0.f};
#pragma unroll
    for (int mt = 0; mt < 2; ++mt)
#pragma unroll
        for (int r = 0; r < 16; ++r) {
            int o = 64 * w + 32 * mt + (r & 3) + 8 * (r >> 2) + 4 * g2;
            float bo = bias[o], ao = amap[o];
#pragma unroll
            for (int nt = 0; nt < 2; ++nt)
                part[nt] += ao * fast_tanh(acc[mt][nt][r] + bo);
        }
#pragma unroll
    for (int nt = 0; nt < 2; ++nt) {
        float p = part[nt];
        p += __shfl_xor(p, 32);
        if (lane < 32) red[w][nt * 32 + lane] = p;
    }
    __syncthreads();
    if (tid < 64) alpha[e0 + tid] = red[0][tid] + red[1][tid] + red[2][tid] + red[3][tid];
}

// ---------------- per-node segment softmax + weighted aggregate ----------------
__global__ void k_aggregate(
    const float* __restrict__ x, const int* __restrict__ src,
    const float* __restrict__ alpha, const int* __restrict__ rowptr,
    const int* __restrict__ elist, float* __restrict__ agg)
{
    int gw = (blockIdx.x * blockDim.x + threadIdx.x) >> 6;
    int lane = threadIdx.x & 63;
    if (gw >= NODES) return;
    int start = rowptr[gw], end = rowptr[gw + 1];
    int deg = end - start;
    float m = -INFINITY;
    for (int i = lane; i < deg; i += 64) m = fmaxf(m, alpha[elist[start + i]]);
#pragma unroll
    for (int off = 32; off > 0; off >>= 1) m = fmaxf(m, __shfl_xor(m, off));
    float ssum = 0.f;
    for (int i = lane; i < deg; i += 64) ssum += expf(alpha[elist[start + i]] - m);
#pragma unroll
    for (int off = 32; off > 0; off >>= 1) ssum += __shfl_xor(ssum, off);
    float a0 = 0.f, a1 = 0.f, a2 = 0.f, a3 = 0.f;
    for (int i = 0; i < deg; ++i) {
        int e = elist[start + i];
        float w = expf(alpha[e] - m);
        const float4 v = *(const float4*)(x + (size_t)src[e] * DIM + lane * 4);
        a0 += w * v.x; a1 += w * v.y; a2 += w * v.z; a3 += w * v.w;
    }
    float inv = 1.f / (ssum + 1e-16f);
    float4 r; r.x = a0 * inv; r.y = a1 * inv; r.z = a2 * inv; r.w = a3 * inv;
    *(float4*)(agg + (size_t)gw * DIM + lane * 4) = r;
}

// ---------------- out = agg@pwa^T + x@pwo^T + biases ----------------
__global__ __launch_bounds__(256, 2) void k_out(
    const float* __restrict__ agg, const float* __restrict__ x,
    const float* __restrict__ Wa, const float* __restrict__ Wo,
    const float* __restrict__ ba, const float* __restrict__ bo,
    float* __restrict__ outb)
{
    __shared__ float As[256][36];
    __shared__ float Bs[64][36];
    __shared__ float Cs[64][68];
    const int tid = threadIdx.x;
    const int oo = tid >> 3, ee = tid & 7;
    const int n0 = blockIdx.x * 64;
    const int bn = tid >> 2, bks = tid & 3;

    float acc[8][8];
#pragma unroll
    for (int j = 0; j < 8; ++j)
#pragma unroll
        for (int je = 0; je < 8; ++je) acc[j][je] = 0.f;

    for (int cc = 0; cc < 16; ++cc) {
        const float* Wsrc = (cc < 8) ? Wa : Wo;
        const float* Bsrc = (cc < 8) ? agg : x;
        const int kc = (cc & 7) * 32;
        {
            const float4* g = (const float4*)(Wsrc + (size_t)tid * DIM + kc);
            float4* l = (float4*)(&As[tid][0]);
#pragma unroll
            for (int i = 0; i < 8; ++i) l[i] = g[i];
        }
        {
            const float4* g = (const float4*)(Bsrc + (size_t)(n0 + bn) * DIM + kc + bks * 8);
            *(float4*)(&Bs[bn][bks * 8])     = g[0];
            *(float4*)(&Bs[bn][bks * 8 + 4]) = g[1];
        }
        __syncthreads();
#pragma unroll
        for (int kq = 0; kq < 8; ++kq) {
            float4 av[8], bv[8];
#pragma unroll
            for (int j = 0; j < 8; ++j)  av[j] = *(const float4*)(&As[oo + 32 * j][kq * 4]);
#pragma unroll
            for (int je = 0; je < 8; ++je) bv[je] = *(const float4*)(&Bs[ee + 8 * je][kq * 4]);
#pragma unroll
            for (int j = 0; j < 8; ++j)
#pragma unroll
                for (int je = 0; je < 8; ++je) {
                    acc[j][je] += av[j].x * bv[je].x;
                    acc[j][je] += av[j].y * bv[je].y;
                    acc[j][je] += av[j].z * bv[je].z;
                    acc[j][je] += av[j].w * bv[je].w;
                }
        }
        __syncthreads();
    }

    float bsum[8];
#pragma unroll
    for (int j = 0; j < 8; ++j) bsum[j] = ba[oo + 32 * j] + bo[oo + 32 * j];

    for (int c = 0; c < 4; ++c) {
#pragma unroll
        for (int jh = 0; jh < 2; ++jh) {
            int j = 2 * c + jh;
#pragma unroll
            for (int je = 0; je < 8; ++je)
                Cs[ee + 8 * je][oo + 32 * jh] = acc[j][je] + bsum[j];
        }
        __syncthreads();
        int ol = tid & 63, wv = tid >> 6;
        for (int r = wv; r < 64; r += 4)
            outb[(size_t)(n0 + r) * DIM + c * 64 + ol] = Cs[r][ol];
        __syncthreads();
    }
}

// ---------------- BN column stats (fp64 partials) ----------------
__global__ void k_colstat(const float* __restrict__ outb, double* __restrict__ psum,
                          double* __restrict__ psq) {
    int g = blockIdx.x, t = threadIdx.x;
    double s = 0.0, q = 0.0;
    const float* p = outb + (size_t)g * 256 * DIM + t;
    for (int r = 0; r < 256; ++r) { double v = (double)p[(size_t)r * DIM]; s += v; q += v * v; }
    psum[g * DIM + t] = s;
    psq[g * DIM + t] = q;
}

__global__ void k_bnparam(const double* __restrict__ psum, const double* __restrict__ psq,
                          const float* __restrict__ gamma, const float* __restrict__ beta,
                          float* __restrict__ scale, float* __restrict__ shift) {
    int t = threadIdx.x;
    double s = 0.0, q = 0.0;
    for (int g = 0; g < 32; ++g) { s += psum[g * DIM + t]; q += psq[g * DIM + t]; }
    double mean = s / (double)NODES;
    double var = q / (double)NODES - mean * mean;
    float sc = (float)((double)gamma[t] / sqrt(var + 1e-5));
    scale[t] = sc;
    shift[t] = (float)((double)beta[t] - mean * (double)sc);
}

// ---------------- affine + SELU + pooling score ----------------
__global__ void k_bnselu(float* __restrict__ outb, const float* __restrict__ scale,
                         const float* __restrict__ shift, const float* __restrict__ yw,
                         const float* __restrict__ yb, float* __restrict__ y) {
    int gw = (blockIdx.x * blockDim.x + threadIdx.x) >> 6;
    int lane = threadIdx.x & 63;
    if (gw >= NODES) return;
    float4 v  = *(const float4*)(outb + (size_t)gw * DIM + lane * 4);
    float4 sc = *(const float4*)(scale + lane * 4);
    float4 sh = *(const float4*)(shift + lane * 4);
    const float SL = 1.0507009873554805f, SA = 1.6732632423543772f;
    float4 o;
    o.x = v.x * sc.x + sh.x;
    o.y = v.y * sc.y + sh.y;
    o.z = v.z * sc.z + sh.z;
    o.w = v.w * sc.w + sh.w;
    o.x = (o.x > 0.f) ? SL * o.x : SL * SA * expm1f(o.x);
    o.y = (o.y > 0.f) ? SL * o.y : SL * SA * expm1f(o.y);
    o.z = (o.z > 0.f) ? SL * o.z : SL * SA * expm1f(o.z);
    o.w = (o.w > 0.f) ? SL * o.w : SL * SA * expm1f(o.w);
    *(float4*)(outb + (size_t)gw * DIM + lane * 4) = o;
    float4 w = *(const float4*)(yw + lane * 4);
    float z = o.x * w.x + o.y * w.y + o.z * w.z + o.w * w.w;
#pragma unroll
    for (int off = 32; off > 0; off >>= 1) z += __shfl_xor(z, off);
    if (lane == 0) y[gw] = 1.f / (1.f + expf(-(z + yb[0])));
}

// ---------------- per-batch bitonic top-k (val desc, idx asc — jax semantics) ----------------
__global__ void k_topk(const float* __restrict__ y, float* __restrict__ svals,
                       int* __restrict__ sidx) {
    __shared__ float v[1024];
    __shared__ int  id[1024];
    int b = blockIdx.x, t = threadIdx.x;   // 512 threads
    v[t] = y[b * 1024 + t];           id[t] = t;
    v[t + 512] = y[b * 1024 + t + 512]; id[t + 512] = t + 512;
    __syncthreads();
    for (int k = 2; k <= 1024; k <<= 1) {
        for (int j = k >> 1; j > 0; j >>= 1) {
            for (int i = t; i < 1024; i += 512) {
                int l = i ^ j;
                if (l > i) {
                    float vi = v[i], vl = v[l];
                    int ii = id[i], il = id[l];
                    bool precede = (vi > vl) || (vi == vl && ii < il);
                    bool dirDesc = ((i & k) == 0);
                    bool sw = dirDesc ? !precede : precede;
                    if (sw) { v[i] = vl; v[l] = vi; id[i] = il; id[l] = ii; }
                }
            }
            __syncthreads();
        }
    }
    if (t < 512) { svals[b * 512 + t] = v[t]; sidx[b * 512 + t] = id[t]; }
}

// ---------------- gather + gate ----------------
__global__ void k_gather(const float* __restrict__ outb, const float* __restrict__ svals,
                         const int* __restrict__ sidx, float* __restrict__ dout) {
    int gw = (blockIdx.x * blockDim.x + threadIdx.x) >> 6;
    int lane = threadIdx.x & 63;
    int b = gw >> 9, r = gw & 511;
    float val = svals[b * 512 + r];
    int idn = sidx[b * 512 + r];
    float4 vv = *(const float4*)(outb + (size_t)(b * 1024 + idn) * DIM + lane * 4);
    vv.x *= val; vv.y *= val; vv.z *= val; vv.w *= val;
    *(float4*)(dout + (size_t)(b * 512 + r) * DIM + lane * 4) = vv;
}

extern "C" void kernel_launch(void* const* d_in, const int* in_sizes, int n_in,
                              void* d_out, int out_size, void* d_ws, size_t ws_size,
                              hipStream_t stream) {
    const float* x     = (const float*)d_in[0];
    const int* edges   = (const int*)d_in[1];
    const float* att_w = (const float*)d_in[2];
    const float* att_b = (const float*)d_in[3];
    const float* amap  = (const float*)d_in[4];
    const float* pwa_w = (const float*)d_in[5];
    const float* pwa_b = (const float*)d_in[6];
    const float* pwo_w = (const float*)d_in[7];
    const float* pwo_b = (const float*)d_in[8];
    const float* gamma = (const float*)d_in[9];
    const float* beta  = (const float*)d_in[10];
    const float* yw    = (const float*)d_in[11];
    const float* yb    = (const float*)d_in[12];
    float* out = (float*)d_out;
    const int* src = edges;
    const int* dst = edges + NEDGE;

    char* ws = (char*)d_ws;
    size_t off = 0;
    auto alloc = [&](size_t b) { void* p = ws + off; off = (off + b + 255) & ~(size_t)255; return p; };
    float* alpha  = (float*)alloc((size_t)NEDGE * 4);
    int*   elist  = (int*)alloc((size_t)NEDGE * 4);
    float* agg    = (float*)alloc((size_t)NODES * DIM * 4);
    float* outb   = (float*)alloc((size_t)NODES * DIM * 4);
    int*   deg    = (int*)alloc(NODES * 4);
    int*   rowptr = (int*)alloc((NODES + 1) * 4);
    int*   cursor = (int*)alloc(NODES * 4);
    double* psum  = (double*)alloc(32 * DIM * 8);
    double* psq   = (double*)alloc(32 * DIM * 8);
    float* scale  = (float*)alloc(DIM * 4);
    float* shift  = (float*)alloc(DIM * 4);
    float* yv     = (float*)alloc(NODES * 4);
    float* svals  = (float*)alloc(8 * 512 * 4);
    int*   sidx   = (int*)alloc(8 * 512 * 4);
    u16*   wf     = (u16*)alloc((size_t)16 * 4 * 6 * 512 * 2);

    k_wfrag<<<32, 256, 0, stream>>>(att_w, wf);
    k_zero<<<NODES / 256, 256, 0, stream>>>(deg);
    k_deg<<<NEDGE / 256, 256, 0, stream>>>(dst, deg);
    k_scan<<<1, 256, 0, stream>>>(deg, rowptr, cursor);
    k_fill<<<NEDGE / 256, 256, 0, stream>>>(dst, cursor, elist);
    k_alpha_v6<<<NEDGE / 64, 256, 0, stream>>>(x, src, dst, wf, att_b, amap, alpha);
    k_aggregate<<<NODES / 4, 256, 0, stream>>>(x, src, alpha, rowptr, elist, agg);
    k_out<<<NODES / 64, 256, 0, stream>>>(agg, x, pwa_w, pwo_w, pwa_b, pwo_b, outb);
    k_colstat<<<32, 256, 0, stream>>>(outb, psum, psq);
    k_bnparam<<<1, 256, 0, stream>>>(psum, psq, gamma, beta, scale, shift);
    k_bnselu<<<NODES / 4, 256, 0, stream>>>(outb, scale, shift, yw, yb, yv);
    k_topk<<<8, 512, 0, stream>>>(yv, svals, sidx);
    k_gather<<<(8 * 512) / 4, 256, 0, stream>>>(outb, svals, sidx, out);
}